// Round 2
// baseline (936.165 us; speedup 1.0000x reference)
//
#include <hip/hip_runtime.h>
#include <stdint.h>

typedef __attribute__((ext_vector_type(8))) short bf16x8;
typedef __attribute__((ext_vector_type(8))) unsigned short ushort8;
typedef __attribute__((ext_vector_type(4))) float f32x4;

constexpr int DM = 1024;   // d_model
constexpr int SQ = 2048;   // seq len
constexpr int NB = 2;      // batch
constexpr int NH = 16;     // heads
constexpr int DK = 64;     // head dim
constexpr int M  = NB * SQ; // 4096 rows

__device__ inline float bf2f(unsigned short u) {
    union { uint32_t i; float f; } c; c.i = ((uint32_t)u) << 16; return c.f;
}
__device__ inline unsigned short f2bf(float f) {
    union { float f; uint32_t i; } c; c.f = f;
    uint32_t r = c.i + 0x7FFFu + ((c.i >> 16) & 1u);   // round-to-nearest-even
    return (unsigned short)(r >> 16);
}

// ---------------- fp32 -> bf16 convert (x) ----------------
__global__ __launch_bounds__(256) void cvt_x(const float* __restrict__ x,
                                             unsigned short* __restrict__ xb) {
    int idx = (blockIdx.x * 256 + threadIdx.x) * 8;
    const float* p = x + idx;
    ushort8 o;
#pragma unroll
    for (int i = 0; i < 8; ++i) o[i] = f2bf(p[i]);
    *(ushort8*)(xb + idx) = o;
}

// ------------- fp32 [K][N] -> bf16 [N][K] transpose-convert -------------
__global__ __launch_bounds__(256) void cvt_w(const float* __restrict__ W,
                                             unsigned short* __restrict__ Wt) {
    __shared__ float tile[32][33];
    int tx = threadIdx.x, ty = threadIdx.y;
    int bx = blockIdx.x, by = blockIdx.y;
#pragma unroll
    for (int j = 0; j < 4; ++j)
        tile[ty + j * 8][tx] = W[(size_t)(by * 32 + ty + j * 8) * DM + bx * 32 + tx];
    __syncthreads();
#pragma unroll
    for (int j = 0; j < 4; ++j)
        Wt[(size_t)(bx * 32 + ty + j * 8) * DM + by * 32 + tx] = f2bf(tile[tx][ty + j * 8]);
}

// ---------------- bf16 MFMA GEMM, 64x64 tile, BK=32 ----------------
// C[M,N] = A[M,K] * Bt[N,K]^T + bias
// MODE 0: write bf16 head-split [B,H,S,DK];  MODE 1: write fp32 row-major [M,N]
template <int MODE>
__global__ __launch_bounds__(256) void gemm64(const unsigned short* __restrict__ A,
                                              const unsigned short* __restrict__ Bt,
                                              const float* __restrict__ bias,
                                              void* __restrict__ outp) {
    constexpr int K = 1024;
    __shared__ unsigned short As[64 * 32];
    __shared__ unsigned short Bs[64 * 32];
    const int t = threadIdx.x;
    const int w = t >> 6, l = t & 63;
    const int bx = blockIdx.x, by = blockIdx.y;
    f32x4 acc[4] = {};

    const int r = t >> 2, kc = (t & 3) * 8;
    const unsigned short* Ap = A + (size_t)(by * 64 + r) * K + kc;
    const unsigned short* Bp = Bt + (size_t)(bx * 64 + r) * K + kc;
    const int a_off = (w * 16 + (l & 15)) * 32 + (l >> 4) * 8;

    for (int k0 = 0; k0 < K; k0 += 32) {
        *(bf16x8*)&As[r * 32 + kc] = *(const bf16x8*)Ap;
        *(bf16x8*)&Bs[r * 32 + kc] = *(const bf16x8*)Bp;
        Ap += 32; Bp += 32;
        __syncthreads();
        bf16x8 af = *(const bf16x8*)&As[a_off];
#pragma unroll
        for (int nb = 0; nb < 4; ++nb) {
            bf16x8 bfr = *(const bf16x8*)&Bs[(nb * 16 + (l & 15)) * 32 + (l >> 4) * 8];
            acc[nb] = __builtin_amdgcn_mfma_f32_16x16x32_bf16(af, bfr, acc[nb], 0, 0, 0);
        }
        __syncthreads();
    }

#pragma unroll
    for (int nb = 0; nb < 4; ++nb) {
#pragma unroll
        for (int i = 0; i < 4; ++i) {
            int m = by * 64 + w * 16 + (l >> 4) * 4 + i;   // verified C/D row mapping
            int n = bx * 64 + nb * 16 + (l & 15);          // verified C/D col mapping
            float v = acc[nb][i] + bias[n];
            if constexpr (MODE == 0) {
                int b = m >> 11, si = m & 2047;
                int h = n >> 6, d = n & 63;
                ((unsigned short*)outp)[((size_t)(b * NH + h) * SQ + si) * DK + d] = f2bf(v);
            } else {
                ((float*)outp)[(size_t)m * DM + n] = v;
            }
        }
    }
}

// ---------------- causal flash attention, fp32 math ----------------
// Q,K,V: bf16 [B,H,S,DK].  O: bf16 [B,S,DM] (heads re-concatenated).
__global__ __launch_bounds__(256) void attn(const unsigned short* __restrict__ Qg,
                                            const unsigned short* __restrict__ Kg,
                                            const unsigned short* __restrict__ Vg,
                                            unsigned short* __restrict__ O) {
    constexpr int SD = 68;  // padded row stride (floats), 272B: 16B-aligned
    __shared__ float Ks[64 * SD];
    __shared__ float Vs[64 * SD];
    const float NEG_INF = -__builtin_inff();

    const int bid = blockIdx.x;
    const int qt = bid & 31;        // S/64 = 32 q-tiles
    const int bh = bid >> 5;        // b*NH + h
    const int t = threadIdx.x;
    const int r = t >> 2, sub = t & 3;
    const int qg = qt * 64 + r;
    const size_t base = (size_t)bh * SQ * DK;

    // Q row (scaled by 1/sqrt(dk) = 0.125), dims [sub*16, sub*16+16)
    f32x4 qv[4];
    {
        const unsigned short* qp = Qg + base + (size_t)qg * DK + sub * 16;
        ushort8 q0 = *(const ushort8*)qp;
        ushort8 q1 = *(const ushort8*)(qp + 8);
#pragma unroll
        for (int i = 0; i < 8; ++i) {
            qv[i >> 2][i & 3] = bf2f(q0[i]) * 0.125f;
            qv[2 + (i >> 2)][i & 3] = bf2f(q1[i]) * 0.125f;
        }
    }

    float mrun = NEG_INF, lsum = 0.f;
    f32x4 av[4] = {};

    for (int kt = 0; kt <= qt; ++kt) {
        __syncthreads();
        {   // stage 64 K rows + 64 V rows as fp32
            const size_t rowoff = base + (size_t)(kt * 64 + r) * DK + sub * 16;
            ushort8 k0 = *(const ushort8*)(Kg + rowoff);
            ushort8 k1 = *(const ushort8*)(Kg + rowoff + 8);
            ushort8 v0 = *(const ushort8*)(Vg + rowoff);
            ushort8 v1 = *(const ushort8*)(Vg + rowoff + 8);
            f32x4* kd = (f32x4*)&Ks[r * SD + sub * 16];
            f32x4* vd = (f32x4*)&Vs[r * SD + sub * 16];
            f32x4 tmp;
#pragma unroll
            for (int q = 0; q < 2; ++q) {
#pragma unroll
                for (int c4 = 0; c4 < 4; ++c4) tmp[c4] = bf2f(q ? k1[c4] : k0[c4]);
                kd[q * 2] = tmp;
#pragma unroll
                for (int c4 = 0; c4 < 4; ++c4) tmp[c4] = bf2f(q ? k1[4 + c4] : k0[4 + c4]);
                kd[q * 2 + 1] = tmp;
#pragma unroll
                for (int c4 = 0; c4 < 4; ++c4) tmp[c4] = bf2f(q ? v1[c4] : v0[c4]);
                vd[q * 2] = tmp;
#pragma unroll
                for (int c4 = 0; c4 < 4; ++c4) tmp[c4] = bf2f(q ? v1[4 + c4] : v0[4 + c4]);
                vd[q * 2 + 1] = tmp;
            }
        }
        __syncthreads();

        const int jmaxv = qg - kt * 64;   // local causal bound (>=64 for kt<qt)
#pragma unroll 1
        for (int c = 0; c < 64; c += 32) {
            float s[32];
#pragma unroll
            for (int j = 0; j < 32; ++j) {
                int jj = c + j;
                const f32x4* kr = (const f32x4*)&Ks[jj * SD + sub * 16];
                float d = 0.f;
#pragma unroll
                for (int i4 = 0; i4 < 4; ++i4) {
                    f32x4 kv = kr[i4];
                    d += qv[i4][0] * kv[0] + qv[i4][1] * kv[1] +
                         qv[i4][2] * kv[2] + qv[i4][3] * kv[3];
                }
                d += __shfl_xor(d, 1);
                d += __shfl_xor(d, 2);
                s[j] = (jj <= jmaxv) ? d : NEG_INF;
            }
            float tmax = NEG_INF;
#pragma unroll
            for (int j = 0; j < 32; ++j) tmax = fmaxf(tmax, s[j]);
            float mn = fmaxf(mrun, tmax);     // finite from the first chunk onward
            float corr = __expf(mrun - mn);   // exp(-inf)=0 on the first chunk
            lsum *= corr;
#pragma unroll
            for (int i4 = 0; i4 < 4; ++i4) av[i4] *= corr;
#pragma unroll
            for (int j = 0; j < 32; ++j) {
                float p = __expf(s[j] - mn);  // masked -> exp(-inf)=0
                lsum += p;
                const f32x4* vr = (const f32x4*)&Vs[(c + j) * SD + sub * 16];
#pragma unroll
                for (int i4 = 0; i4 < 4; ++i4) av[i4] += vr[i4] * p;
            }
            mrun = mn;
        }
    }

    float inv = 1.f / lsum;
    const int b = bh >> 4, h = bh & 15;
    unsigned short* op = O + ((size_t)(b * SQ + qg)) * DM + h * DK + sub * 16;
    ushort8 o0, o1;
#pragma unroll
    for (int i = 0; i < 8; ++i) {
        o0[i] = f2bf(av[i >> 2][i & 3] * inv);
        o1[i] = f2bf(av[2 + (i >> 2)][i & 3] * inv);
    }
    *(ushort8*)op = o0;
    *(ushort8*)(op + 8) = o1;
}

extern "C" void kernel_launch(void* const* d_in, const int* in_sizes, int n_in,
                              void* d_out, int out_size, void* d_ws, size_t ws_size,
                              hipStream_t stream) {
    const float* x  = (const float*)d_in[0];
    const float* Wq = (const float*)d_in[1];
    const float* bq = (const float*)d_in[2];
    const float* Wk = (const float*)d_in[3];
    const float* bk = (const float*)d_in[4];
    const float* Wv = (const float*)d_in[5];
    const float* bv = (const float*)d_in[6];
    const float* Wo = (const float*)d_in[7];
    const float* bo = (const float*)d_in[8];
    float* out = (float*)d_out;

    char* ws = (char*)d_ws;
    const size_t XB_BYTES = (size_t)M * DM * 2;        // 8 MB
    const size_t W_BYTES  = (size_t)DM * DM * 2;       // 2 MB
    const size_t H_BYTES  = (size_t)NB * NH * SQ * DK * 2; // 8 MB
    unsigned short* xb  = (unsigned short*)ws;                         // x bf16; later aliased as O
    unsigned short* wqt = (unsigned short*)(ws + XB_BYTES);
    unsigned short* wkt = (unsigned short*)(ws + XB_BYTES + W_BYTES);
    unsigned short* wvt = (unsigned short*)(ws + XB_BYTES + 2 * W_BYTES);
    unsigned short* wot = (unsigned short*)(ws + XB_BYTES + 3 * W_BYTES);
    unsigned short* Qb  = (unsigned short*)(ws + XB_BYTES + 4 * W_BYTES);
    unsigned short* Kb  = (unsigned short*)(ws + XB_BYTES + 4 * W_BYTES + H_BYTES);
    unsigned short* Vb  = (unsigned short*)(ws + XB_BYTES + 4 * W_BYTES + 2 * H_BYTES);

    cvt_x<<<(M * DM) / (256 * 8), 256, 0, stream>>>(x, xb);
    dim3 wgrid(32, 32), wblk(32, 8);
    cvt_w<<<wgrid, wblk, 0, stream>>>(Wq, wqt);
    cvt_w<<<wgrid, wblk, 0, stream>>>(Wk, wkt);
    cvt_w<<<wgrid, wblk, 0, stream>>>(Wv, wvt);
    cvt_w<<<wgrid, wblk, 0, stream>>>(Wo, wot);

    dim3 ggrid(DM / 64, M / 64);   // (16, 64)
    gemm64<0><<<ggrid, 256, 0, stream>>>(xb, wqt, bq, Qb);
    gemm64<0><<<ggrid, 256, 0, stream>>>(xb, wkt, bk, Kb);
    gemm64<0><<<ggrid, 256, 0, stream>>>(xb, wvt, bv, Vb);

    attn<<<NB * NH * (SQ / 64), 256, 0, stream>>>(Qb, Kb, Vb, xb /* O aliases xb */);

    gemm64<1><<<ggrid, 256, 0, stream>>>(xb, wot, bo, out);
}

// Round 3
// 209.681 us; speedup vs baseline: 4.4647x; 4.4647x over previous
//
#include <hip/hip_runtime.h>
#include <stdint.h>

typedef __attribute__((ext_vector_type(8))) short bf16x8;
typedef __attribute__((ext_vector_type(8))) unsigned short ushort8;
typedef __attribute__((ext_vector_type(4))) float f32x4;

constexpr int DM = 1024;   // d_model
constexpr int SQ = 2048;   // seq len
constexpr int NB = 2;      // batch
constexpr int NH = 16;     // heads
constexpr int DK = 64;     // head dim
constexpr int M  = NB * SQ; // 4096 rows

__device__ inline float bf2f(unsigned short u) {
    union { uint32_t i; float f; } c; c.i = ((uint32_t)u) << 16; return c.f;
}
__device__ inline unsigned short f2bf(float f) {
    union { float f; uint32_t i; } c; c.f = f;
    uint32_t r = c.i + 0x7FFFu + ((c.i >> 16) & 1u);   // round-to-nearest-even
    return (unsigned short)(r >> 16);
}

// ---------------- fp32 -> bf16 convert (x) ----------------
__global__ __launch_bounds__(256) void cvt_x(const float* __restrict__ x,
                                             unsigned short* __restrict__ xb) {
    int idx = (blockIdx.x * 256 + threadIdx.x) * 8;
    const float* p = x + idx;
    ushort8 o;
#pragma unroll
    for (int i = 0; i < 8; ++i) o[i] = f2bf(p[i]);
    *(ushort8*)(xb + idx) = o;
}

// ------------- fp32 [K][N] -> bf16 [N][K] transpose-convert -------------
__global__ __launch_bounds__(256) void cvt_w(const float* __restrict__ W,
                                             unsigned short* __restrict__ Wt) {
    __shared__ float tile[32][33];
    int tx = threadIdx.x, ty = threadIdx.y;
    int bx = blockIdx.x, by = blockIdx.y;
#pragma unroll
    for (int j = 0; j < 4; ++j)
        tile[ty + j * 8][tx] = W[(size_t)(by * 32 + ty + j * 8) * DM + bx * 32 + tx];
    __syncthreads();
#pragma unroll
    for (int j = 0; j < 4; ++j)
        Wt[(size_t)(bx * 32 + ty + j * 8) * DM + by * 32 + tx] = f2bf(tile[tx][ty + j * 8]);
}

// ---------------- bf16 MFMA GEMM, 64x64 tile, BK=32 ----------------
// C[M,N] = A[M,K] * Bt[N,K]^T + bias
// MODE 0: write bf16 head-split [B,H,S,DK];  MODE 1: write fp32 row-major [M,N]
template <int MODE>
__global__ __launch_bounds__(256) void gemm64(const unsigned short* __restrict__ A,
                                              const unsigned short* __restrict__ Bt,
                                              const float* __restrict__ bias,
                                              void* __restrict__ outp) {
    constexpr int K = 1024;
    __shared__ unsigned short As[64 * 32];
    __shared__ unsigned short Bs[64 * 32];
    const int t = threadIdx.x;
    const int w = t >> 6, l = t & 63;
    const int bx = blockIdx.x, by = blockIdx.y;
    f32x4 acc[4] = {};

    const int r = t >> 2, kc = (t & 3) * 8;
    const unsigned short* Ap = A + (size_t)(by * 64 + r) * K + kc;
    const unsigned short* Bp = Bt + (size_t)(bx * 64 + r) * K + kc;
    const int a_off = (w * 16 + (l & 15)) * 32 + (l >> 4) * 8;

    for (int k0 = 0; k0 < K; k0 += 32) {
        *(bf16x8*)&As[r * 32 + kc] = *(const bf16x8*)Ap;
        *(bf16x8*)&Bs[r * 32 + kc] = *(const bf16x8*)Bp;
        Ap += 32; Bp += 32;
        __syncthreads();
        bf16x8 af = *(const bf16x8*)&As[a_off];
#pragma unroll
        for (int nb = 0; nb < 4; ++nb) {
            bf16x8 bfr = *(const bf16x8*)&Bs[(nb * 16 + (l & 15)) * 32 + (l >> 4) * 8];
            acc[nb] = __builtin_amdgcn_mfma_f32_16x16x32_bf16(af, bfr, acc[nb], 0, 0, 0);
        }
        __syncthreads();
    }

#pragma unroll
    for (int nb = 0; nb < 4; ++nb) {
#pragma unroll
        for (int i = 0; i < 4; ++i) {
            int m = by * 64 + w * 16 + (l >> 4) * 4 + i;   // verified C/D row mapping
            int n = bx * 64 + nb * 16 + (l & 15);          // verified C/D col mapping
            float v = acc[nb][i] + bias[n];
            if constexpr (MODE == 0) {
                int b = m >> 11, si = m & 2047;
                int h = n >> 6, d = n & 63;
                ((unsigned short*)outp)[((size_t)(b * NH + h) * SQ + si) * DK + d] = f2bf(v);
            } else {
                ((float*)outp)[(size_t)m * DM + n] = v;
            }
        }
    }
}

// ---------------- MFMA causal flash attention ----------------
// Q,K,V: bf16 [B,H,S,DK].  O: bf16 [B,S,DM] (heads re-concatenated).
// Block: 4 waves x 16 q-rows = 64-row q-tile; KV tile = 64.
// Each block handles TWO q-tiles (qt, 31-qt) -> constant 33 kv-iterations/block.
constexpr int SDK = 72;   // padded LDS row stride (bf16 elements), 144 B: 16B-aligned
__global__ __launch_bounds__(256) void attn_mfma(const unsigned short* __restrict__ Qg,
                                                 const unsigned short* __restrict__ Kg,
                                                 const unsigned short* __restrict__ Vg,
                                                 unsigned short* __restrict__ O) {
    __shared__ __align__(16) unsigned short Ks[64 * SDK];     // [key][dim]
    __shared__ __align__(16) unsigned short Vt[64 * SDK];     // [dim][key] (transposed)
    __shared__ __align__(16) unsigned short Pl[4][16 * SDK];  // per-wave P [qrow][key]
    const float NEG_INF = -__builtin_inff();

    const int bid  = blockIdx.x;
    const int bh   = bid >> 4;       // 0..31 = b*NH + h
    const int pair = bid & 15;       // 0..15
    const int b = bh >> 4, h = bh & 15;
    const size_t base = (size_t)bh * SQ * DK;

    const int t = threadIdx.x;
    const int w = t >> 6, l = t & 63;
    const int l15 = l & 15, lg = l >> 4;   // lg in 0..3

    // staging role: thread t stages key row (t&63), dims w*16..w*16+16
    const int skey = l;
    const int sd0  = w * 16;

#pragma unroll 1
    for (int half = 0; half < 2; ++half) {
        const int qt = half ? (31 - pair) : pair;

        // Q A-fragment for this wave's 16 rows: A[row=l15][k=lg*8+j] (+32 for chunk 1)
        const int qrow = qt * 64 + w * 16 + l15;
        const unsigned short* qp = Qg + base + (size_t)qrow * DK + lg * 8;
        bf16x8 aq0 = *(const bf16x8*)qp;
        bf16x8 aq1 = *(const bf16x8*)(qp + 32);

        float m_run[4], l_run[4];
        f32x4 oacc[4];
#pragma unroll
        for (int i = 0; i < 4; ++i) { m_run[i] = NEG_INF; l_run[i] = 0.f; }
#pragma unroll
        for (int nb = 0; nb < 4; ++nb) oacc[nb] = (f32x4){0.f, 0.f, 0.f, 0.f};

#pragma unroll 1
        for (int kt = 0; kt <= qt; ++kt) {
            __syncthreads();   // protect Ks/Vt from previous iteration's readers
            {
                const size_t rowoff = base + (size_t)(kt * 64 + skey) * DK + sd0;
                bf16x8 k0 = *(const bf16x8*)(Kg + rowoff);
                bf16x8 k1 = *(const bf16x8*)(Kg + rowoff + 8);
                ushort8 v0 = *(const ushort8*)(Vg + rowoff);
                ushort8 v1 = *(const ushort8*)(Vg + rowoff + 8);
                *(bf16x8*)&Ks[skey * SDK + sd0] = k0;
                *(bf16x8*)&Ks[skey * SDK + sd0 + 8] = k1;
#pragma unroll
                for (int i = 0; i < 8; ++i) {
                    Vt[(sd0 + i) * SDK + skey] = v0[i];
                    Vt[(sd0 + 8 + i) * SDK + skey] = v1[i];
                }
            }
            __syncthreads();

            // ---- S = Q K^T for 16 rows x 64 keys ----
            f32x4 sacc[4];
#pragma unroll
            for (int nb = 0; nb < 4; ++nb) sacc[nb] = (f32x4){0.f, 0.f, 0.f, 0.f};
#pragma unroll
            for (int nb = 0; nb < 4; ++nb) {
                const unsigned short* kb = &Ks[(nb * 16 + l15) * SDK + lg * 8];
                bf16x8 bk0 = *(const bf16x8*)kb;
                bf16x8 bk1 = *(const bf16x8*)(kb + 32);
                sacc[nb] = __builtin_amdgcn_mfma_f32_16x16x32_bf16(aq0, bk0, sacc[nb], 0, 0, 0);
                sacc[nb] = __builtin_amdgcn_mfma_f32_16x16x32_bf16(aq1, bk1, sacc[nb], 0, 0, 0);
            }

            // ---- scale + causal mask (only diag tile needs masking) ----
            float s[4][4];
            const bool diag = (kt == qt);
#pragma unroll
            for (int nb = 0; nb < 4; ++nb)
#pragma unroll
                for (int i = 0; i < 4; ++i) {
                    float v = sacc[nb][i] * 0.125f;
                    if (diag && (nb * 16 + l15 > w * 16 + lg * 4 + i)) v = NEG_INF;
                    s[nb][i] = v;
                }

            // ---- online softmax (rows live across the 16-lane group) ----
            float mt[4], corr[4];
#pragma unroll
            for (int i = 0; i < 4; ++i)
                mt[i] = fmaxf(fmaxf(s[0][i], s[1][i]), fmaxf(s[2][i], s[3][i]));
#pragma unroll
            for (int d = 1; d < 16; d <<= 1)
#pragma unroll
                for (int i = 0; i < 4; ++i) mt[i] = fmaxf(mt[i], __shfl_xor(mt[i], d));
#pragma unroll
            for (int i = 0; i < 4; ++i) {
                float mn = fmaxf(m_run[i], mt[i]);
                corr[i] = __expf(m_run[i] - mn);   // first tile: exp(-inf)=0
                m_run[i] = mn;
            }
            float p[4][4], ls[4] = {0.f, 0.f, 0.f, 0.f};
#pragma unroll
            for (int nb = 0; nb < 4; ++nb)
#pragma unroll
                for (int i = 0; i < 4; ++i) {
                    float pv = __expf(s[nb][i] - m_run[i]);   // masked -> 0
                    p[nb][i] = pv;
                    ls[i] += pv;
                }
#pragma unroll
            for (int d = 1; d < 16; d <<= 1)
#pragma unroll
                for (int i = 0; i < 4; ++i) ls[i] += __shfl_xor(ls[i], d);
#pragma unroll
            for (int i = 0; i < 4; ++i) l_run[i] = l_run[i] * corr[i] + ls[i];
#pragma unroll
            for (int nb = 0; nb < 4; ++nb)
#pragma unroll
                for (int i = 0; i < 4; ++i) oacc[nb][i] *= corr[i];

            // ---- P -> LDS (verified C/D layout) and re-read as A-fragment ----
#pragma unroll
            for (int nb = 0; nb < 4; ++nb)
#pragma unroll
                for (int i = 0; i < 4; ++i)
                    Pl[w][(lg * 4 + i) * SDK + nb * 16 + l15] = f2bf(p[nb][i]);
            // same-wave write->read: compiler inserts the lgkmcnt wait
            bf16x8 ap0 = *(const bf16x8*)&Pl[w][l15 * SDK + lg * 8];
            bf16x8 ap1 = *(const bf16x8*)&Pl[w][l15 * SDK + 32 + lg * 8];

            // ---- O += P V  (B-fragment from transposed Vt: contiguous keys) ----
#pragma unroll
            for (int nb = 0; nb < 4; ++nb) {
                const unsigned short* vb = &Vt[(nb * 16 + l15) * SDK + lg * 8];
                bf16x8 bv0 = *(const bf16x8*)vb;
                bf16x8 bv1 = *(const bf16x8*)(vb + 32);
                oacc[nb] = __builtin_amdgcn_mfma_f32_16x16x32_bf16(ap0, bv0, oacc[nb], 0, 0, 0);
                oacc[nb] = __builtin_amdgcn_mfma_f32_16x16x32_bf16(ap1, bv1, oacc[nb], 0, 0, 0);
            }
        }

        // ---- epilogue: normalize and write O (bf16 [B,S,DM]) ----
        float inv[4];
#pragma unroll
        for (int i = 0; i < 4; ++i) inv[i] = 1.f / l_run[i];
#pragma unroll
        for (int nb = 0; nb < 4; ++nb)
#pragma unroll
            for (int i = 0; i < 4; ++i) {
                int row = qt * 64 + w * 16 + lg * 4 + i;
                int col = h * 64 + nb * 16 + l15;
                O[((size_t)(b * SQ + row)) * DM + col] = f2bf(oacc[nb][i] * inv[i]);
            }
    }
}

extern "C" void kernel_launch(void* const* d_in, const int* in_sizes, int n_in,
                              void* d_out, int out_size, void* d_ws, size_t ws_size,
                              hipStream_t stream) {
    const float* x  = (const float*)d_in[0];
    const float* Wq = (const float*)d_in[1];
    const float* bq = (const float*)d_in[2];
    const float* Wk = (const float*)d_in[3];
    const float* bk = (const float*)d_in[4];
    const float* Wv = (const float*)d_in[5];
    const float* bv = (const float*)d_in[6];
    const float* Wo = (const float*)d_in[7];
    const float* bo = (const float*)d_in[8];
    float* out = (float*)d_out;

    char* ws = (char*)d_ws;
    const size_t XB_BYTES = (size_t)M * DM * 2;        // 8 MB
    const size_t W_BYTES  = (size_t)DM * DM * 2;       // 2 MB
    const size_t H_BYTES  = (size_t)NB * NH * SQ * DK * 2; // 8 MB
    unsigned short* xb  = (unsigned short*)ws;                         // x bf16; later aliased as O
    unsigned short* wqt = (unsigned short*)(ws + XB_BYTES);
    unsigned short* wkt = (unsigned short*)(ws + XB_BYTES + W_BYTES);
    unsigned short* wvt = (unsigned short*)(ws + XB_BYTES + 2 * W_BYTES);
    unsigned short* wot = (unsigned short*)(ws + XB_BYTES + 3 * W_BYTES);
    unsigned short* Qb  = (unsigned short*)(ws + XB_BYTES + 4 * W_BYTES);
    unsigned short* Kb  = (unsigned short*)(ws + XB_BYTES + 4 * W_BYTES + H_BYTES);
    unsigned short* Vb  = (unsigned short*)(ws + XB_BYTES + 4 * W_BYTES + 2 * H_BYTES);

    cvt_x<<<(M * DM) / (256 * 8), 256, 0, stream>>>(x, xb);
    dim3 wgrid(32, 32), wblk(32, 8);
    cvt_w<<<wgrid, wblk, 0, stream>>>(Wq, wqt);
    cvt_w<<<wgrid, wblk, 0, stream>>>(Wk, wkt);
    cvt_w<<<wgrid, wblk, 0, stream>>>(Wv, wvt);
    cvt_w<<<wgrid, wblk, 0, stream>>>(Wo, wot);

    dim3 ggrid(DM / 64, M / 64);   // (16, 64)
    gemm64<0><<<ggrid, 256, 0, stream>>>(xb, wqt, bq, Qb);
    gemm64<0><<<ggrid, 256, 0, stream>>>(xb, wkt, bk, Kb);
    gemm64<0><<<ggrid, 256, 0, stream>>>(xb, wvt, bv, Vb);

    attn_mfma<<<NB * NH * 16, 256, 0, stream>>>(Qb, Kb, Vb, xb /* O aliases xb */);

    gemm64<1><<<ggrid, 256, 0, stream>>>(xb, wot, bo, out);
}

// Round 8
// 171.105 us; speedup vs baseline: 5.4713x; 1.2255x over previous
//
// r8: identical to r4 kernel; resubmitted due to repeated UnresponsiveContainer (no GPU signal since r3)
#include <hip/hip_runtime.h>
#include <stdint.h>

typedef __attribute__((ext_vector_type(8))) short bf16x8;
typedef __attribute__((ext_vector_type(8))) unsigned short ushort8;
typedef __attribute__((ext_vector_type(4))) float f32x4;

constexpr int DM = 1024;   // d_model
constexpr int SQ = 2048;   // seq len
constexpr int NB = 2;      // batch
constexpr int NH = 16;     // heads
constexpr int DK = 64;     // head dim
constexpr int M  = NB * SQ; // 4096 rows

__device__ inline float bf2f(unsigned short u) {
    union { uint32_t i; float f; } c; c.i = ((uint32_t)u) << 16; return c.f;
}
__device__ inline unsigned short f2bf(float f) {
    union { float f; uint32_t i; } c; c.f = f;
    uint32_t r = c.i + 0x7FFFu + ((c.i >> 16) & 1u);   // round-to-nearest-even
    return (unsigned short)(r >> 16);
}

__device__ inline void gload_lds16(const unsigned short* g, unsigned short* l) {
    __builtin_amdgcn_global_load_lds(
        (const __attribute__((address_space(1))) void*)g,
        (__attribute__((address_space(3))) void*)l, 16, 0, 0);
}

// ---------------- fp32 -> bf16 convert (x) ----------------
__global__ __launch_bounds__(256) void cvt_x(const float* __restrict__ x,
                                             unsigned short* __restrict__ xb) {
    int idx = (blockIdx.x * 256 + threadIdx.x) * 8;
    const float* p = x + idx;
    ushort8 o;
#pragma unroll
    for (int i = 0; i < 8; ++i) o[i] = f2bf(p[i]);
    *(ushort8*)(xb + idx) = o;
}

// ------------- fp32 [K][N] -> bf16 [N][K] transpose-convert -------------
__global__ __launch_bounds__(256) void cvt_w(const float* __restrict__ W,
                                             unsigned short* __restrict__ Wt) {
    __shared__ float tile[32][33];
    int tx = threadIdx.x, ty = threadIdx.y;
    int bx = blockIdx.x, by = blockIdx.y;
#pragma unroll
    for (int j = 0; j < 4; ++j)
        tile[ty + j * 8][tx] = W[(size_t)(by * 32 + ty + j * 8) * DM + bx * 32 + tx];
    __syncthreads();
#pragma unroll
    for (int j = 0; j < 4; ++j)
        Wt[(size_t)(bx * 32 + ty + j * 8) * DM + by * 32 + tx] = f2bf(tile[tx][ty + j * 8]);
}

// ---------------- bf16 MFMA GEMM, 128x128 tile, BK=32 (m97 structure) ----------------
// C[M,N] = A[M,K] * Bt[N,K]^T + bias
// MODE 0: write bf16 head-split [3][B,H,S,DK] (fused QKV, bias selected by n>>10)
// MODE 1: write fp32 row-major [M,DM]
template <int MODE>
__global__ __launch_bounds__(256) void gemm128(const unsigned short* __restrict__ A,
                                               const unsigned short* __restrict__ Bt,
                                               const float* __restrict__ b0,
                                               const float* __restrict__ b1,
                                               const float* __restrict__ b2,
                                               void* __restrict__ outp) {
    constexpr int K = 1024;
    __shared__ __align__(16) unsigned short As[128 * 32];
    __shared__ __align__(16) unsigned short Bs[128 * 32];
    const int t = threadIdx.x;
    const int w = t >> 6, l = t & 63;
    const int l15 = l & 15, lg = l >> 4;
    const int wr = w >> 1, wc = w & 1;
    const int bx = blockIdx.x, by = blockIdx.y;

    f32x4 acc[4][4] = {};

    const int srow = l >> 2;        // 0..15 row within a 16-row staging group
    const int sk   = (l & 3) * 8;   // k-chunk (8 bf16 = 16B)
    const unsigned short* Abase = A  + (size_t)(by * 128) * K;
    const unsigned short* Bbase = Bt + (size_t)(bx * 128) * K;

    for (int k0 = 0; k0 < K; k0 += 32) {
#pragma unroll
        for (int i = 0; i < 2; ++i) {
            const int row = w * 32 + i * 16 + srow;   // wave w stages rows w*32..w*32+32
            gload_lds16(Abase + (size_t)row * K + k0 + sk, &As[row * 32 + sk]);
            gload_lds16(Bbase + (size_t)row * K + k0 + sk, &Bs[row * 32 + sk]);
        }
        __syncthreads();   // drains vmcnt -> staged tile visible

        bf16x8 af[4], bfr[4];
#pragma unroll
        for (int mi = 0; mi < 4; ++mi)
            af[mi] = *(const bf16x8*)&As[(wr * 64 + mi * 16 + l15) * 32 + lg * 8];
#pragma unroll
        for (int ni = 0; ni < 4; ++ni)
            bfr[ni] = *(const bf16x8*)&Bs[(wc * 64 + ni * 16 + l15) * 32 + lg * 8];
#pragma unroll
        for (int mi = 0; mi < 4; ++mi)
#pragma unroll
            for (int ni = 0; ni < 4; ++ni)
                acc[mi][ni] = __builtin_amdgcn_mfma_f32_16x16x32_bf16(af[mi], bfr[ni], acc[mi][ni], 0, 0, 0);
        __syncthreads();   // protect LDS reuse
    }

    // ---- epilogue ----
#pragma unroll
    for (int ni = 0; ni < 4; ++ni) {
        const int n = bx * 128 + wc * 64 + ni * 16 + l15;
        float bias;
        if constexpr (MODE == 0) {
            const int mat = n >> 10;   // wave-uniform (128-tile never spans matrices)
            const float* bp = (mat == 0) ? b0 : (mat == 1) ? b1 : b2;
            bias = bp[n & 1023];
        } else {
            bias = b0[n];
        }
#pragma unroll
        for (int mi = 0; mi < 4; ++mi)
#pragma unroll
            for (int i = 0; i < 4; ++i) {
                const int m = by * 128 + wr * 64 + mi * 16 + lg * 4 + i;
                const float v = acc[mi][ni][i] + bias;
                if constexpr (MODE == 0) {
                    const int mat = n >> 10, c = n & 1023;
                    const int h = c >> 6, d = c & 63;
                    const int b = m >> 11, si = m & 2047;
                    ((unsigned short*)outp)[(size_t)mat * (NB * NH * SQ * DK) +
                        ((size_t)(b * NH + h) * SQ + si) * DK + d] = f2bf(v);
                } else {
                    ((float*)outp)[(size_t)m * DM + n] = v;
                }
            }
    }
}

// ---------------- MFMA causal flash attention ----------------
// Q,K,V: bf16 [B,H,S,DK].  O: bf16 [B,S,DM] (heads re-concatenated).
// Block: 4 waves x 16 q-rows = 64-row q-tile; KV tile = 64.
// Each block handles TWO q-tiles (qt, 31-qt) -> constant 33 kv-iterations/block.
constexpr int SDK = 72;   // padded LDS row stride (bf16 elements), 144 B: 16B-aligned
__global__ __launch_bounds__(256) void attn_mfma(const unsigned short* __restrict__ Qg,
                                                 const unsigned short* __restrict__ Kg,
                                                 const unsigned short* __restrict__ Vg,
                                                 unsigned short* __restrict__ O) {
    __shared__ __align__(16) unsigned short Ks[64 * SDK];     // [key][dim]
    __shared__ __align__(16) unsigned short Vt[64 * SDK];     // [dim][key] (transposed)
    __shared__ __align__(16) unsigned short Pl[4][16 * SDK];  // per-wave P [qrow][key]
    const float NEG_INF = -__builtin_inff();

    const int bid  = blockIdx.x;
    const int bh   = bid >> 4;       // 0..31 = b*NH + h
    const int pair = bid & 15;       // 0..15
    const int b = bh >> 4, h = bh & 15;
    const size_t base = (size_t)bh * SQ * DK;

    const int t = threadIdx.x;
    const int w = t >> 6, l = t & 63;
    const int l15 = l & 15, lg = l >> 4;   // lg in 0..3

    // staging role: thread t stages key row (t&63), dims w*16..w*16+16
    const int skey = l;
    const int sd0  = w * 16;

#pragma unroll 1
    for (int half = 0; half < 2; ++half) {
        const int qt = half ? (31 - pair) : pair;

        // Q A-fragment for this wave's 16 rows: A[row=l15][k=lg*8+j] (+32 for chunk 1)
        const int qrow = qt * 64 + w * 16 + l15;
        const unsigned short* qp = Qg + base + (size_t)qrow * DK + lg * 8;
        bf16x8 aq0 = *(const bf16x8*)qp;
        bf16x8 aq1 = *(const bf16x8*)(qp + 32);

        float m_run[4], l_run[4];
        f32x4 oacc[4];
#pragma unroll
        for (int i = 0; i < 4; ++i) { m_run[i] = NEG_INF; l_run[i] = 0.f; }
#pragma unroll
        for (int nb = 0; nb < 4; ++nb) oacc[nb] = (f32x4){0.f, 0.f, 0.f, 0.f};

#pragma unroll 1
        for (int kt = 0; kt <= qt; ++kt) {
            __syncthreads();   // protect Ks/Vt from previous iteration's readers
            {
                const size_t rowoff = base + (size_t)(kt * 64 + skey) * DK + sd0;
                bf16x8 k0 = *(const bf16x8*)(Kg + rowoff);
                bf16x8 k1 = *(const bf16x8*)(Kg + rowoff + 8);
                ushort8 v0 = *(const ushort8*)(Vg + rowoff);
                ushort8 v1 = *(const ushort8*)(Vg + rowoff + 8);
                *(bf16x8*)&Ks[skey * SDK + sd0] = k0;
                *(bf16x8*)&Ks[skey * SDK + sd0 + 8] = k1;
#pragma unroll
                for (int i = 0; i < 8; ++i) {
                    Vt[(sd0 + i) * SDK + skey] = v0[i];
                    Vt[(sd0 + 8 + i) * SDK + skey] = v1[i];
                }
            }
            __syncthreads();

            // ---- S = Q K^T for 16 rows x 64 keys ----
            f32x4 sacc[4];
#pragma unroll
            for (int nb = 0; nb < 4; ++nb) sacc[nb] = (f32x4){0.f, 0.f, 0.f, 0.f};
#pragma unroll
            for (int nb = 0; nb < 4; ++nb) {
                const unsigned short* kb = &Ks[(nb * 16 + l15) * SDK + lg * 8];
                bf16x8 bk0 = *(const bf16x8*)kb;
                bf16x8 bk1 = *(const bf16x8*)(kb + 32);
                sacc[nb] = __builtin_amdgcn_mfma_f32_16x16x32_bf16(aq0, bk0, sacc[nb], 0, 0, 0);
                sacc[nb] = __builtin_amdgcn_mfma_f32_16x16x32_bf16(aq1, bk1, sacc[nb], 0, 0, 0);
            }

            // ---- scale + causal mask (only diag tile needs masking) ----
            float s[4][4];
            const bool diag = (kt == qt);
#pragma unroll
            for (int nb = 0; nb < 4; ++nb)
#pragma unroll
                for (int i = 0; i < 4; ++i) {
                    float v = sacc[nb][i] * 0.125f;
                    if (diag && (nb * 16 + l15 > w * 16 + lg * 4 + i)) v = NEG_INF;
                    s[nb][i] = v;
                }

            // ---- online softmax (rows live across the 16-lane group) ----
            float mt[4], corr[4];
#pragma unroll
            for (int i = 0; i < 4; ++i)
                mt[i] = fmaxf(fmaxf(s[0][i], s[1][i]), fmaxf(s[2][i], s[3][i]));
#pragma unroll
            for (int d = 1; d < 16; d <<= 1)
#pragma unroll
                for (int i = 0; i < 4; ++i) mt[i] = fmaxf(mt[i], __shfl_xor(mt[i], d));
#pragma unroll
            for (int i = 0; i < 4; ++i) {
                float mn = fmaxf(m_run[i], mt[i]);
                corr[i] = __expf(m_run[i] - mn);   // first tile: exp(-inf)=0
                m_run[i] = mn;
            }
            float p[4][4], ls[4] = {0.f, 0.f, 0.f, 0.f};
#pragma unroll
            for (int nb = 0; nb < 4; ++nb)
#pragma unroll
                for (int i = 0; i < 4; ++i) {
                    float pv = __expf(s[nb][i] - m_run[i]);   // masked -> 0
                    p[nb][i] = pv;
                    ls[i] += pv;
                }
#pragma unroll
            for (int d = 1; d < 16; d <<= 1)
#pragma unroll
                for (int i = 0; i < 4; ++i) ls[i] += __shfl_xor(ls[i], d);
#pragma unroll
            for (int i = 0; i < 4; ++i) l_run[i] = l_run[i] * corr[i] + ls[i];
#pragma unroll
            for (int nb = 0; nb < 4; ++nb)
#pragma unroll
                for (int i = 0; i < 4; ++i) oacc[nb][i] *= corr[i];

            // ---- P -> LDS (verified C/D layout) and re-read as A-fragment ----
#pragma unroll
            for (int nb = 0; nb < 4; ++nb)
#pragma unroll
                for (int i = 0; i < 4; ++i)
                    Pl[w][(lg * 4 + i) * SDK + nb * 16 + l15] = f2bf(p[nb][i]);
            // same-wave write->read: compiler inserts the lgkmcnt wait
            bf16x8 ap0 = *(const bf16x8*)&Pl[w][l15 * SDK + lg * 8];
            bf16x8 ap1 = *(const bf16x8*)&Pl[w][l15 * SDK + 32 + lg * 8];

            // ---- O += P V  (B-fragment from transposed Vt: contiguous keys) ----
#pragma unroll
            for (int nb = 0; nb < 4; ++nb) {
                const unsigned short* vb = &Vt[(nb * 16 + l15) * SDK + lg * 8];
                bf16x8 bv0 = *(const bf16x8*)vb;
                bf16x8 bv1 = *(const bf16x8*)(vb + 32);
                oacc[nb] = __builtin_amdgcn_mfma_f32_16x16x32_bf16(ap0, bv0, oacc[nb], 0, 0, 0);
                oacc[nb] = __builtin_amdgcn_mfma_f32_16x16x32_bf16(ap1, bv1, oacc[nb], 0, 0, 0);
            }
        }

        // ---- epilogue: normalize and write O (bf16 [B,S,DM]) ----
        float inv[4];
#pragma unroll
        for (int i = 0; i < 4; ++i) inv[i] = 1.f / l_run[i];
#pragma unroll
        for (int nb = 0; nb < 4; ++nb)
#pragma unroll
            for (int i = 0; i < 4; ++i) {
                int row = qt * 64 + w * 16 + lg * 4 + i;
                int col = h * 64 + nb * 16 + l15;
                O[((size_t)(b * SQ + row)) * DM + col] = f2bf(oacc[nb][i] * inv[i]);
            }
    }
}

extern "C" void kernel_launch(void* const* d_in, const int* in_sizes, int n_in,
                              void* d_out, int out_size, void* d_ws, size_t ws_size,
                              hipStream_t stream) {
    const float* x  = (const float*)d_in[0];
    const float* Wq = (const float*)d_in[1];
    const float* bq = (const float*)d_in[2];
    const float* Wk = (const float*)d_in[3];
    const float* bk = (const float*)d_in[4];
    const float* Wv = (const float*)d_in[5];
    const float* bv = (const float*)d_in[6];
    const float* Wo = (const float*)d_in[7];
    const float* bo = (const float*)d_in[8];
    float* out = (float*)d_out;

    char* ws = (char*)d_ws;
    const size_t XB_BYTES = (size_t)M * DM * 2;        // 8 MB
    const size_t W_BYTES  = (size_t)DM * DM * 2;       // 2 MB
    const size_t H_BYTES  = (size_t)NB * NH * SQ * DK * 2; // 8 MB
    unsigned short* xb  = (unsigned short*)ws;                         // x bf16; later aliased as O
    unsigned short* wqt = (unsigned short*)(ws + XB_BYTES);            // wqt/wkt/wvt contiguous ->
    unsigned short* wkt = (unsigned short*)(ws + XB_BYTES + W_BYTES);  //   one [3072][1024] Bt
    unsigned short* wvt = (unsigned short*)(ws + XB_BYTES + 2 * W_BYTES);
    unsigned short* wot = (unsigned short*)(ws + XB_BYTES + 3 * W_BYTES);
    unsigned short* Qb  = (unsigned short*)(ws + XB_BYTES + 4 * W_BYTES); // Qb/Kb/Vb contiguous
    unsigned short* Kb  = (unsigned short*)(ws + XB_BYTES + 4 * W_BYTES + H_BYTES);
    unsigned short* Vb  = (unsigned short*)(ws + XB_BYTES + 4 * W_BYTES + 2 * H_BYTES);

    cvt_x<<<(M * DM) / (256 * 8), 256, 0, stream>>>(x, xb);
    dim3 wgrid(32, 32), wblk(32, 8);
    cvt_w<<<wgrid, wblk, 0, stream>>>(Wq, wqt);
    cvt_w<<<wgrid, wblk, 0, stream>>>(Wk, wkt);
    cvt_w<<<wgrid, wblk, 0, stream>>>(Wv, wvt);
    cvt_w<<<wgrid, wblk, 0, stream>>>(Wo, wot);

    // fused QKV projection: N = 3072, grid 24x32 = 768 blocks = 3/CU
    gemm128<0><<<dim3(24, 32), 256, 0, stream>>>(xb, wqt, bq, bk, bv, Qb);

    attn_mfma<<<NB * NH * 16, 256, 0, stream>>>(Qb, Kb, Vb, xb /* O aliases xb */);

    // output projection: N = 1024
    gemm128<1><<<dim3(8, 32), 256, 0, stream>>>(xb, wot, bo, bo, bo, out);
}

// Round 9
// 155.330 us; speedup vs baseline: 6.0269x; 1.1016x over previous
//
// r9: attn rewritten: 32x32 MFMA, swapped QK^T (q=lane&31), in-register P via cvt_pk+shfl_xor(32),
//     V^T produced by QKV-GEMM epilogue, K/V staged via global_load_lds w/ pre-swizzled source.
#include <hip/hip_runtime.h>
#include <stdint.h>

typedef __attribute__((ext_vector_type(8))) short bf16x8;
typedef __attribute__((ext_vector_type(8))) unsigned short ushort8;
typedef __attribute__((ext_vector_type(4))) float f32x4;
typedef __attribute__((ext_vector_type(16))) float f32x16;

constexpr int DM = 1024;   // d_model
constexpr int SQ = 2048;   // seq len
constexpr int NB = 2;      // batch
constexpr int NH = 16;     // heads
constexpr int DK = 64;     // head dim
constexpr int M  = NB * SQ; // 4096 rows

__device__ inline float bf2f(unsigned short u) {
    union { uint32_t i; float f; } c; c.i = ((uint32_t)u) << 16; return c.f;
}
__device__ inline unsigned short f2bf(float f) {
    union { float f; uint32_t i; } c; c.f = f;
    uint32_t r = c.i + 0x7FFFu + ((c.i >> 16) & 1u);   // round-to-nearest-even
    return (unsigned short)(r >> 16);
}
__device__ inline uint32_t cvtpk(float lo, float hi) {
    uint32_t r;
    asm("v_cvt_pk_bf16_f32 %0, %1, %2" : "=v"(r) : "v"(lo), "v"(hi));
    return r;
}
__device__ inline uint32_t sx32(uint32_t v) {   // exchange with partner lane (l ^ 32)
    return (uint32_t)__shfl_xor((int)v, 32);
}
__device__ inline bf16x8 mkfrag(uint32_t a, uint32_t b, uint32_t c, uint32_t d) {
    union { bf16x8 v; uint32_t u[4]; } m;
    m.u[0] = a; m.u[1] = b; m.u[2] = c; m.u[3] = d;
    return m.v;
}
__device__ inline void gload_lds16(const unsigned short* g, unsigned short* l) {
    __builtin_amdgcn_global_load_lds(
        (const __attribute__((address_space(1))) void*)g,
        (__attribute__((address_space(3))) void*)l, 16, 0, 0);
}

// ---------------- fp32 -> bf16 convert (x) ----------------
__global__ __launch_bounds__(256) void cvt_x(const float* __restrict__ x,
                                             unsigned short* __restrict__ xb) {
    int idx = (blockIdx.x * 256 + threadIdx.x) * 8;
    const float* p = x + idx;
    ushort8 o;
#pragma unroll
    for (int i = 0; i < 8; ++i) o[i] = f2bf(p[i]);
    *(ushort8*)(xb + idx) = o;
}

// ------------- fp32 [K][N] -> bf16 [N][K] transpose-convert -------------
__global__ __launch_bounds__(256) void cvt_w(const float* __restrict__ W,
                                             unsigned short* __restrict__ Wt) {
    __shared__ float tile[32][33];
    int tx = threadIdx.x, ty = threadIdx.y;
    int bx = blockIdx.x, by = blockIdx.y;
#pragma unroll
    for (int j = 0; j < 4; ++j)
        tile[ty + j * 8][tx] = W[(size_t)(by * 32 + ty + j * 8) * DM + bx * 32 + tx];
    __syncthreads();
#pragma unroll
    for (int j = 0; j < 4; ++j)
        Wt[(size_t)(bx * 32 + ty + j * 8) * DM + by * 32 + tx] = f2bf(tile[tx][ty + j * 8]);
}

// ---------------- bf16 MFMA GEMM, 128x128 tile, BK=32 (m97 structure) ----------------
// MODE 0: fused QKV. Q,K written [B,H,S,DK]; V written TRANSPOSED [B,H,DK,S].
// MODE 1: fp32 row-major [M,DM].
template <int MODE>
__global__ __launch_bounds__(256) void gemm128(const unsigned short* __restrict__ A,
                                               const unsigned short* __restrict__ Bt,
                                               const float* __restrict__ b0,
                                               const float* __restrict__ b1,
                                               const float* __restrict__ b2,
                                               void* __restrict__ outp) {
    constexpr int K = 1024;
    __shared__ __align__(16) unsigned short As[128 * 32];
    __shared__ __align__(16) unsigned short Bs[128 * 32];
    const int t = threadIdx.x;
    const int w = t >> 6, l = t & 63;
    const int l15 = l & 15, lg = l >> 4;
    const int wr = w >> 1, wc = w & 1;
    const int bx = blockIdx.x, by = blockIdx.y;

    f32x4 acc[4][4] = {};

    const int srow = l >> 2;
    const int sk   = (l & 3) * 8;
    const unsigned short* Abase = A  + (size_t)(by * 128) * K;
    const unsigned short* Bbase = Bt + (size_t)(bx * 128) * K;

    for (int k0 = 0; k0 < K; k0 += 32) {
#pragma unroll
        for (int i = 0; i < 2; ++i) {
            const int row = w * 32 + i * 16 + srow;
            gload_lds16(Abase + (size_t)row * K + k0 + sk, &As[row * 32 + sk]);
            gload_lds16(Bbase + (size_t)row * K + k0 + sk, &Bs[row * 32 + sk]);
        }
        __syncthreads();

        bf16x8 af[4], bfr[4];
#pragma unroll
        for (int mi = 0; mi < 4; ++mi)
            af[mi] = *(const bf16x8*)&As[(wr * 64 + mi * 16 + l15) * 32 + lg * 8];
#pragma unroll
        for (int ni = 0; ni < 4; ++ni)
            bfr[ni] = *(const bf16x8*)&Bs[(wc * 64 + ni * 16 + l15) * 32 + lg * 8];
#pragma unroll
        for (int mi = 0; mi < 4; ++mi)
#pragma unroll
            for (int ni = 0; ni < 4; ++ni)
                acc[mi][ni] = __builtin_amdgcn_mfma_f32_16x16x32_bf16(af[mi], bfr[ni], acc[mi][ni], 0, 0, 0);
        __syncthreads();
    }

#pragma unroll
    for (int ni = 0; ni < 4; ++ni) {
        const int n = bx * 128 + wc * 64 + ni * 16 + l15;
        float bias;
        if constexpr (MODE == 0) {
            const int mat = n >> 10;   // wave-uniform
            const float* bp = (mat == 0) ? b0 : (mat == 1) ? b1 : b2;
            bias = bp[n & 1023];
        } else {
            bias = b0[n];
        }
#pragma unroll
        for (int mi = 0; mi < 4; ++mi)
#pragma unroll
            for (int i = 0; i < 4; ++i) {
                const int m = by * 128 + wr * 64 + mi * 16 + lg * 4 + i;
                const float v = acc[mi][ni][i] + bias;
                if constexpr (MODE == 0) {
                    const int mat = n >> 10, c = n & 1023;
                    const int h = c >> 6, d = c & 63;
                    const int b = m >> 11, si = m & 2047;
                    size_t idx;
                    if (mat == 2)   // V transposed: [B,H,DK,S]
                        idx = ((size_t)(b * NH + h) * DK + d) * SQ + si;
                    else
                        idx = ((size_t)(b * NH + h) * SQ + si) * DK + d;
                    ((unsigned short*)outp)[(size_t)mat * (NB * NH * SQ * DK) + idx] = f2bf(v);
                } else {
                    ((float*)outp)[(size_t)m * DM + n] = v;
                }
            }
    }
}

// ---------------- 32x32-MFMA causal flash attention ----------------
// Q,K: bf16 [B,H,S,DK]; Vt: bf16 [B,H,DK,S]; O: bf16 [B,S,DM].
// Block: 2 waves x 32 q-rows = 64-row q-tile; kv-tile 64; pair (qt, 31-qt) -> 33 iters.
// Swapped QK^T: S^T = mfma(K, Q) -> lane owns q = lane&31. Softmax in-lane + 1 shfl(32).
// PV: O^T = mfma(Vt, P) -> lane still owns q. P assembled in-reg (cvt_pk + 8 shfl(32)).
// K/Vt staged via global_load_lds, pre-swizzled source; reads use byte ^= (row&7)<<4.
__global__ __launch_bounds__(128) void attn32(const unsigned short* __restrict__ Qg,
                                              const unsigned short* __restrict__ Kg,
                                              const unsigned short* __restrict__ Vtg,
                                              unsigned short* __restrict__ O) {
    __shared__ __align__(16) char KsB[8192];   // [64 keys][64 dims], swizzled 16B slots
    __shared__ __align__(16) char VsB[8192];   // [64 dims][64 keys], swizzled 16B slots
    const float NEG_INF = -__builtin_inff();

    const int bid   = blockIdx.x;
    const int bh    = bid >> 4;       // 0..31
    const int pairi = bid & 15;       // 0..15
    const int b = bh >> 4, h = bh & 15;
    const size_t base = (size_t)bh * SQ * DK;

    const int t = threadIdx.x;        // 0..127
    const int w = t >> 6, l = t & 63;
    const int l31 = l & 31, hi = l >> 5;
    const bool h0 = (hi == 0);

    // staging lane constants: lane covers LDS row (i*8 + l>>3), slot (l&7);
    // source chunk = slot ^ (row&7) = (l&7) ^ (l>>3)  (i*8 multiple of 8)
    const int lrow = l >> 3;
    const int lchunk = (l & 7) ^ lrow;
    const unsigned short* ksrc0 = Kg + base + (size_t)lrow * DK + lchunk * 8;
    const unsigned short* vsrc0 = Vtg + (size_t)(bh * 64 + lrow) * SQ + lchunk * 8;

    // swizzled read byte-offsets for dim/key chunk c (c=0..3): slot = (hi + 2c) ^ (row&7)
    int roff[4];
#pragma unroll
    for (int c = 0; c < 4; ++c) roff[c] = (hi * 16 + 32 * c) ^ ((l & 7) << 4);
    const int rb0 = l31 * 128, rb1 = (32 + l31) * 128;

#pragma unroll 1
    for (int half = 0; half < 2; ++half) {
        const int qt = half ? (31 - pairi) : pairi;
        const int qrow = qt * 64 + w * 32 + l31;
        const int qloc = w * 32 + l31;

        // Q B-fragments: lane holds Q[q=l31][hi*8 + 16c + j]
        bf16x8 qf[4];
        {
            const unsigned short* qp = Qg + base + (size_t)qrow * DK + hi * 8;
#pragma unroll
            for (int c = 0; c < 4; ++c) qf[c] = *(const bf16x8*)(qp + 16 * c);
        }

        float mrun = NEG_INF, lsum = 0.f;
        f32x16 o0 = {}, o1 = {};

#pragma unroll 1
        for (int kt = 0; kt <= qt; ++kt) {
            __syncthreads();   // previous tile's reads done
            {
                const unsigned short* ks = ksrc0 + (size_t)kt * 64 * DK;
                const unsigned short* vs = vsrc0 + kt * 64;
                if (w == 0) {
#pragma unroll
                    for (int i = 0; i < 8; ++i)
                        gload_lds16(ks + i * 8 * DK, (unsigned short*)(KsB + i * 1024) + l * 8);
                } else {
#pragma unroll
                    for (int i = 0; i < 8; ++i)
                        gload_lds16(vs + (size_t)i * 8 * SQ, (unsigned short*)(VsB + i * 1024) + l * 8);
                }
            }
            __syncthreads();   // drains vmcnt -> tile visible

            // ---- S^T = K Q^T : D[key][q], lane owns q = l31 ----
            f32x16 s0 = {}, s1 = {};
#pragma unroll
            for (int c = 0; c < 4; ++c) {
                bf16x8 ka0 = *(const bf16x8*)(KsB + rb0 + roff[c]);
                bf16x8 ka1 = *(const bf16x8*)(KsB + rb1 + roff[c]);
                s0 = __builtin_amdgcn_mfma_f32_32x32x16_bf16(ka0, qf[c], s0, 0, 0, 0);
                s1 = __builtin_amdgcn_mfma_f32_32x32x16_bf16(ka1, qf[c], s1, 0, 0, 0);
            }

            // ---- scale + causal mask + in-lane softmax ----
            const bool diag = (kt == qt);
            float p[32];
            float tm = NEG_INF;
#pragma unroll
            for (int r = 0; r < 16; ++r) {
                const int key0 = (r & 3) + 8 * (r >> 2) + 4 * hi;   // verified C/D row map
                float v0 = s0[r] * 0.125f;
                float v1 = s1[r] * 0.125f;
                if (diag && key0 > qloc) v0 = NEG_INF;
                if (diag && key0 + 32 > qloc) v1 = NEG_INF;
                p[r] = v0; p[16 + r] = v1;
                tm = fmaxf(tm, fmaxf(v0, v1));
            }
            tm = fmaxf(tm, __shfl_xor(tm, 32));   // partner holds other 32 keys
            const float mn = fmaxf(mrun, tm);
            const float corr = __expf(mrun - mn); // first tile: exp(-inf)=0
            mrun = mn;
            float ps = 0.f;
#pragma unroll
            for (int r = 0; r < 32; ++r) { p[r] = __expf(p[r] - mn); ps += p[r]; }
            lsum = lsum * corr + ps;
#pragma unroll
            for (int r = 0; r < 16; ++r) { o0[r] *= corr; o1[r] *= corr; }

            // ---- P -> bf16 packs + partner exchange -> PV B-fragments ----
            uint32_t pk[16];
#pragma unroll
            for (int i = 0; i < 16; ++i) pk[i] = cvtpk(p[2 * i], p[2 * i + 1]);
            const uint32_t X1 = sx32(h0 ? pk[2]  : pk[0]);
            const uint32_t X2 = sx32(h0 ? pk[3]  : pk[1]);
            const uint32_t X3 = sx32(h0 ? pk[6]  : pk[4]);
            const uint32_t X4 = sx32(h0 ? pk[7]  : pk[5]);
            const uint32_t X5 = sx32(h0 ? pk[10] : pk[8]);
            const uint32_t X6 = sx32(h0 ? pk[11] : pk[9]);
            const uint32_t X7 = sx32(h0 ? pk[14] : pk[12]);
            const uint32_t X8 = sx32(h0 ? pk[15] : pk[13]);
            bf16x8 pf[4];
            pf[0] = mkfrag(h0 ? pk[0]  : X1, h0 ? pk[1]  : X2, h0 ? X1 : pk[2],  h0 ? X2 : pk[3]);
            pf[1] = mkfrag(h0 ? pk[4]  : X3, h0 ? pk[5]  : X4, h0 ? X3 : pk[6],  h0 ? X4 : pk[7]);
            pf[2] = mkfrag(h0 ? pk[8]  : X5, h0 ? pk[9]  : X6, h0 ? X5 : pk[10], h0 ? X6 : pk[11]);
            pf[3] = mkfrag(h0 ? pk[12] : X7, h0 ? pk[13] : X8, h0 ? X7 : pk[14], h0 ? X8 : pk[15]);

            // ---- O^T += Vt P : D[d][q], lane owns q = l31 ----
#pragma unroll
            for (int s = 0; s < 4; ++s) {
                bf16x8 va0 = *(const bf16x8*)(VsB + rb0 + roff[s]);
                bf16x8 va1 = *(const bf16x8*)(VsB + rb1 + roff[s]);
                o0 = __builtin_amdgcn_mfma_f32_32x32x16_bf16(va0, pf[s], o0, 0, 0, 0);
                o1 = __builtin_amdgcn_mfma_f32_32x32x16_bf16(va1, pf[s], o1, 0, 0, 0);
            }
        }

        // ---- epilogue: combine partner lsum, normalize, write O ----
        lsum += __shfl_xor(lsum, 32);
        const float inv = 1.f / lsum;
        unsigned short* op = O + ((size_t)(b * SQ + qrow)) * DM + h * 64;
#pragma unroll
        for (int r = 0; r < 16; r += 2) {
            const int d = (r & 3) + 8 * (r >> 2) + 4 * hi;   // d even; d+1 = next reg
            uint32_t w0 = (uint32_t)f2bf(o0[r] * inv) | ((uint32_t)f2bf(o0[r + 1] * inv) << 16);
            uint32_t w1 = (uint32_t)f2bf(o1[r] * inv) | ((uint32_t)f2bf(o1[r + 1] * inv) << 16);
            *(uint32_t*)(op + d) = w0;
            *(uint32_t*)(op + 32 + d) = w1;
        }
    }
}

extern "C" void kernel_launch(void* const* d_in, const int* in_sizes, int n_in,
                              void* d_out, int out_size, void* d_ws, size_t ws_size,
                              hipStream_t stream) {
    const float* x  = (const float*)d_in[0];
    const float* Wq = (const float*)d_in[1];
    const float* bq = (const float*)d_in[2];
    const float* Wk = (const float*)d_in[3];
    const float* bk = (const float*)d_in[4];
    const float* Wv = (const float*)d_in[5];
    const float* bv = (const float*)d_in[6];
    const float* Wo = (const float*)d_in[7];
    const float* bo = (const float*)d_in[8];
    float* out = (float*)d_out;

    char* ws = (char*)d_ws;
    const size_t XB_BYTES = (size_t)M * DM * 2;        // 8 MB
    const size_t W_BYTES  = (size_t)DM * DM * 2;       // 2 MB
    const size_t H_BYTES  = (size_t)NB * NH * SQ * DK * 2; // 8 MB
    unsigned short* xb  = (unsigned short*)ws;                         // x bf16; later aliased as O
    unsigned short* wqt = (unsigned short*)(ws + XB_BYTES);            // wqt/wkt/wvt contiguous
    unsigned short* wkt = (unsigned short*)(ws + XB_BYTES + W_BYTES);
    unsigned short* wvt = (unsigned short*)(ws + XB_BYTES + 2 * W_BYTES);
    unsigned short* wot = (unsigned short*)(ws + XB_BYTES + 3 * W_BYTES);
    unsigned short* Qb  = (unsigned short*)(ws + XB_BYTES + 4 * W_BYTES);
    unsigned short* Kb  = (unsigned short*)(ws + XB_BYTES + 4 * W_BYTES + H_BYTES);
    unsigned short* Vb  = (unsigned short*)(ws + XB_BYTES + 4 * W_BYTES + 2 * H_BYTES); // [B,H,DK,S]

    cvt_x<<<(M * DM) / (256 * 8), 256, 0, stream>>>(x, xb);
    dim3 wgrid(32, 32), wblk(32, 8);
    cvt_w<<<wgrid, wblk, 0, stream>>>(Wq, wqt);
    cvt_w<<<wgrid, wblk, 0, stream>>>(Wk, wkt);
    cvt_w<<<wgrid, wblk, 0, stream>>>(Wv, wvt);
    cvt_w<<<wgrid, wblk, 0, stream>>>(Wo, wot);

    // fused QKV projection: N = 3072, grid 24x32 = 768 blocks = 3/CU
    gemm128<0><<<dim3(24, 32), 256, 0, stream>>>(xb, wqt, bq, bk, bv, Qb);

    attn32<<<NB * NH * 16, 128, 0, stream>>>(Qb, Kb, Vb, xb /* O aliases xb */);

    // output projection: N = 1024
    gemm128<1><<<dim3(8, 32), 256, 0, stream>>>(xb, wot, bo, bo, bo, out);
}

// Round 10
// 153.205 us; speedup vs baseline: 6.1105x; 1.0139x over previous
//
// r10: attn32 occupancy fix: unpaired grid (1024 blk, LPT order) + static double-buffer prefetch.
#include <hip/hip_runtime.h>
#include <stdint.h>

typedef __attribute__((ext_vector_type(8))) short bf16x8;
typedef __attribute__((ext_vector_type(8))) unsigned short ushort8;
typedef __attribute__((ext_vector_type(4))) float f32x4;
typedef __attribute__((ext_vector_type(16))) float f32x16;

constexpr int DM = 1024;   // d_model
constexpr int SQ = 2048;   // seq len
constexpr int NB = 2;      // batch
constexpr int NH = 16;     // heads
constexpr int DK = 64;     // head dim
constexpr int M  = NB * SQ; // 4096 rows

__device__ inline float bf2f(unsigned short u) {
    union { uint32_t i; float f; } c; c.i = ((uint32_t)u) << 16; return c.f;
}
__device__ inline unsigned short f2bf(float f) {
    union { float f; uint32_t i; } c; c.f = f;
    uint32_t r = c.i + 0x7FFFu + ((c.i >> 16) & 1u);   // round-to-nearest-even
    return (unsigned short)(r >> 16);
}
__device__ inline uint32_t cvtpk(float lo, float hi) {
    uint32_t r;
    asm("v_cvt_pk_bf16_f32 %0, %1, %2" : "=v"(r) : "v"(lo), "v"(hi));
    return r;
}
__device__ inline uint32_t sx32(uint32_t v) {   // exchange with partner lane (l ^ 32)
    return (uint32_t)__shfl_xor((int)v, 32);
}
__device__ inline bf16x8 mkfrag(uint32_t a, uint32_t b, uint32_t c, uint32_t d) {
    union { bf16x8 v; uint32_t u[4]; } m;
    m.u[0] = a; m.u[1] = b; m.u[2] = c; m.u[3] = d;
    return m.v;
}
__device__ inline void gload_lds16(const unsigned short* g, unsigned short* l) {
    __builtin_amdgcn_global_load_lds(
        (const __attribute__((address_space(1))) void*)g,
        (__attribute__((address_space(3))) void*)l, 16, 0, 0);
}

// ---------------- fp32 -> bf16 convert (x) ----------------
__global__ __launch_bounds__(256) void cvt_x(const float* __restrict__ x,
                                             unsigned short* __restrict__ xb) {
    int idx = (blockIdx.x * 256 + threadIdx.x) * 8;
    const float* p = x + idx;
    ushort8 o;
#pragma unroll
    for (int i = 0; i < 8; ++i) o[i] = f2bf(p[i]);
    *(ushort8*)(xb + idx) = o;
}

// ------------- fp32 [K][N] -> bf16 [N][K] transpose-convert -------------
__global__ __launch_bounds__(256) void cvt_w(const float* __restrict__ W,
                                             unsigned short* __restrict__ Wt) {
    __shared__ float tile[32][33];
    int tx = threadIdx.x, ty = threadIdx.y;
    int bx = blockIdx.x, by = blockIdx.y;
#pragma unroll
    for (int j = 0; j < 4; ++j)
        tile[ty + j * 8][tx] = W[(size_t)(by * 32 + ty + j * 8) * DM + bx * 32 + tx];
    __syncthreads();
#pragma unroll
    for (int j = 0; j < 4; ++j)
        Wt[(size_t)(bx * 32 + ty + j * 8) * DM + by * 32 + tx] = f2bf(tile[tx][ty + j * 8]);
}

// ---------------- bf16 MFMA GEMM, 128x128 tile, BK=32 (m97 structure) ----------------
// MODE 0: fused QKV. Q,K written [B,H,S,DK]; V written TRANSPOSED [B,H,DK,S].
// MODE 1: fp32 row-major [M,DM].
template <int MODE>
__global__ __launch_bounds__(256) void gemm128(const unsigned short* __restrict__ A,
                                               const unsigned short* __restrict__ Bt,
                                               const float* __restrict__ b0,
                                               const float* __restrict__ b1,
                                               const float* __restrict__ b2,
                                               void* __restrict__ outp) {
    constexpr int K = 1024;
    __shared__ __align__(16) unsigned short As[128 * 32];
    __shared__ __align__(16) unsigned short Bs[128 * 32];
    const int t = threadIdx.x;
    const int w = t >> 6, l = t & 63;
    const int l15 = l & 15, lg = l >> 4;
    const int wr = w >> 1, wc = w & 1;
    const int bx = blockIdx.x, by = blockIdx.y;

    f32x4 acc[4][4] = {};

    const int srow = l >> 2;
    const int sk   = (l & 3) * 8;
    const unsigned short* Abase = A  + (size_t)(by * 128) * K;
    const unsigned short* Bbase = Bt + (size_t)(bx * 128) * K;

    for (int k0 = 0; k0 < K; k0 += 32) {
#pragma unroll
        for (int i = 0; i < 2; ++i) {
            const int row = w * 32 + i * 16 + srow;
            gload_lds16(Abase + (size_t)row * K + k0 + sk, &As[row * 32 + sk]);
            gload_lds16(Bbase + (size_t)row * K + k0 + sk, &Bs[row * 32 + sk]);
        }
        __syncthreads();

        bf16x8 af[4], bfr[4];
#pragma unroll
        for (int mi = 0; mi < 4; ++mi)
            af[mi] = *(const bf16x8*)&As[(wr * 64 + mi * 16 + l15) * 32 + lg * 8];
#pragma unroll
        for (int ni = 0; ni < 4; ++ni)
            bfr[ni] = *(const bf16x8*)&Bs[(wc * 64 + ni * 16 + l15) * 32 + lg * 8];
#pragma unroll
        for (int mi = 0; mi < 4; ++mi)
#pragma unroll
            for (int ni = 0; ni < 4; ++ni)
                acc[mi][ni] = __builtin_amdgcn_mfma_f32_16x16x32_bf16(af[mi], bfr[ni], acc[mi][ni], 0, 0, 0);
        __syncthreads();
    }

#pragma unroll
    for (int ni = 0; ni < 4; ++ni) {
        const int n = bx * 128 + wc * 64 + ni * 16 + l15;
        float bias;
        if constexpr (MODE == 0) {
            const int mat = n >> 10;   // wave-uniform
            const float* bp = (mat == 0) ? b0 : (mat == 1) ? b1 : b2;
            bias = bp[n & 1023];
        } else {
            bias = b0[n];
        }
#pragma unroll
        for (int mi = 0; mi < 4; ++mi)
#pragma unroll
            for (int i = 0; i < 4; ++i) {
                const int m = by * 128 + wr * 64 + mi * 16 + lg * 4 + i;
                const float v = acc[mi][ni][i] + bias;
                if constexpr (MODE == 0) {
                    const int mat = n >> 10, c = n & 1023;
                    const int h = c >> 6, d = c & 63;
                    const int b = m >> 11, si = m & 2047;
                    size_t idx;
                    if (mat == 2)   // V transposed: [B,H,DK,S]
                        idx = ((size_t)(b * NH + h) * DK + d) * SQ + si;
                    else
                        idx = ((size_t)(b * NH + h) * SQ + si) * DK + d;
                    ((unsigned short*)outp)[(size_t)mat * (NB * NH * SQ * DK) + idx] = f2bf(v);
                } else {
                    ((float*)outp)[(size_t)m * DM + n] = v;
                }
            }
    }
}

// ---------------- 32x32-MFMA causal flash attention ----------------
// Q,K: bf16 [B,H,S,DK]; Vt: bf16 [B,H,DK,S]; O: bf16 [B,S,DM].
// Block: 2 waves x 32 q-rows = 64-row q-tile. Grid 1024 (one q-tile each, LPT order).
// Double-buffered K/V staging: prefetch tile kt+1 issued before computing kt.
__global__ __launch_bounds__(128) void attn32(const unsigned short* __restrict__ Qg,
                                              const unsigned short* __restrict__ Kg,
                                              const unsigned short* __restrict__ Vtg,
                                              unsigned short* __restrict__ O) {
    __shared__ __align__(16) char Ks0[8192];   // [64 keys][64 dims], swizzled 16B slots
    __shared__ __align__(16) char Vs0[8192];   // [64 dims][64 keys], swizzled 16B slots
    __shared__ __align__(16) char Ks1[8192];
    __shared__ __align__(16) char Vs1[8192];
    const float NEG_INF = -__builtin_inff();

    const int bid = blockIdx.x;
    const int qt  = 31 - (bid & 31);   // longest blocks dispatched first (LPT)
    const int bh  = bid >> 5;          // 0..31
    const int b = bh >> 4, h = bh & 15;
    const size_t base = (size_t)bh * SQ * DK;

    const int t = threadIdx.x;        // 0..127
    const int w = t >> 6, l = t & 63;
    const int l31 = l & 31, hi = l >> 5;
    const bool h0 = (hi == 0);

    // staging lane constants: lane covers LDS row (i*8 + l>>3), slot (l&7);
    // source chunk = slot ^ (row&7) = (l&7) ^ (l>>3)
    const int lrow = l >> 3;
    const int lchunk = (l & 7) ^ lrow;
    const unsigned short* ksrc0 = Kg + base + (size_t)lrow * DK + lchunk * 8;
    const unsigned short* vsrc0 = Vtg + (size_t)(bh * 64 + lrow) * SQ + lchunk * 8;

    // swizzled read byte-offsets for chunk c: slot = (hi + 2c) ^ (row&7)
    int roff[4];
#pragma unroll
    for (int c = 0; c < 4; ++c) roff[c] = (hi * 16 + 32 * c) ^ ((l & 7) << 4);
    const int rb0 = l31 * 128, rb1 = (32 + l31) * 128;

    const int qrow = qt * 64 + w * 32 + l31;
    const int qloc = w * 32 + l31;

    // Q B-fragments: lane holds Q[q=l31][hi*8 + 16c + j]
    bf16x8 qf[4];
    {
        const unsigned short* qp = Qg + base + (size_t)qrow * DK + hi * 8;
#pragma unroll
        for (int c = 0; c < 4; ++c) qf[c] = *(const bf16x8*)(qp + 16 * c);
    }

    float mrun = NEG_INF, lsum = 0.f;
    f32x16 o0 = {}, o1 = {};

    auto STAGE = [&](int kt, unsigned short* Kd, unsigned short* Vd) {
        if (w == 0) {
            const unsigned short* ks = ksrc0 + (size_t)kt * 64 * DK;
#pragma unroll
            for (int i = 0; i < 8; ++i)
                gload_lds16(ks + i * 8 * DK, Kd + i * 512 + l * 8);
        } else {
            const unsigned short* vs = vsrc0 + kt * 64;
#pragma unroll
            for (int i = 0; i < 8; ++i)
                gload_lds16(vs + (size_t)i * 8 * SQ, Vd + i * 512 + l * 8);
        }
    };

    auto COMPUTE = [&](int kt, const char* KB, const char* VB) {
        // ---- S^T = K Q^T : D[key][q], lane owns q = l31 ----
        f32x16 s0 = {}, s1 = {};
#pragma unroll
        for (int c = 0; c < 4; ++c) {
            bf16x8 ka0 = *(const bf16x8*)(KB + rb0 + roff[c]);
            bf16x8 ka1 = *(const bf16x8*)(KB + rb1 + roff[c]);
            s0 = __builtin_amdgcn_mfma_f32_32x32x16_bf16(ka0, qf[c], s0, 0, 0, 0);
            s1 = __builtin_amdgcn_mfma_f32_32x32x16_bf16(ka1, qf[c], s1, 0, 0, 0);
        }

        // ---- scale + causal mask + in-lane softmax ----
        const bool diag = (kt == qt);
        float p[32];
        float tm = NEG_INF;
#pragma unroll
        for (int r = 0; r < 16; ++r) {
            const int key0 = (r & 3) + 8 * (r >> 2) + 4 * hi;   // verified C/D row map
            float v0 = s0[r] * 0.125f;
            float v1 = s1[r] * 0.125f;
            if (diag && key0 > qloc) v0 = NEG_INF;
            if (diag && key0 + 32 > qloc) v1 = NEG_INF;
            p[r] = v0; p[16 + r] = v1;
            tm = fmaxf(tm, fmaxf(v0, v1));
        }
        tm = fmaxf(tm, __shfl_xor(tm, 32));   // partner holds other 32 keys
        const float mn = fmaxf(mrun, tm);
        const float corr = __expf(mrun - mn); // first tile: exp(-inf)=0
        mrun = mn;
        float ps = 0.f;
#pragma unroll
        for (int r = 0; r < 32; ++r) { p[r] = __expf(p[r] - mn); ps += p[r]; }
        lsum = lsum * corr + ps;
#pragma unroll
        for (int r = 0; r < 16; ++r) { o0[r] *= corr; o1[r] *= corr; }

        // ---- P -> bf16 packs + partner exchange -> PV B-fragments ----
        uint32_t pk[16];
#pragma unroll
        for (int i = 0; i < 16; ++i) pk[i] = cvtpk(p[2 * i], p[2 * i + 1]);
        const uint32_t X1 = sx32(h0 ? pk[2]  : pk[0]);
        const uint32_t X2 = sx32(h0 ? pk[3]  : pk[1]);
        const uint32_t X3 = sx32(h0 ? pk[6]  : pk[4]);
        const uint32_t X4 = sx32(h0 ? pk[7]  : pk[5]);
        const uint32_t X5 = sx32(h0 ? pk[10] : pk[8]);
        const uint32_t X6 = sx32(h0 ? pk[11] : pk[9]);
        const uint32_t X7 = sx32(h0 ? pk[14] : pk[12]);
        const uint32_t X8 = sx32(h0 ? pk[15] : pk[13]);
        bf16x8 pf[4];
        pf[0] = mkfrag(h0 ? pk[0]  : X1, h0 ? pk[1]  : X2, h0 ? X1 : pk[2],  h0 ? X2 : pk[3]);
        pf[1] = mkfrag(h0 ? pk[4]  : X3, h0 ? pk[5]  : X4, h0 ? X3 : pk[6],  h0 ? X4 : pk[7]);
        pf[2] = mkfrag(h0 ? pk[8]  : X5, h0 ? pk[9]  : X6, h0 ? X5 : pk[10], h0 ? X6 : pk[11]);
        pf[3] = mkfrag(h0 ? pk[12] : X7, h0 ? pk[13] : X8, h0 ? X7 : pk[14], h0 ? X8 : pk[15]);

        // ---- O^T += Vt P : D[d][q], lane owns q = l31 ----
#pragma unroll
        for (int s = 0; s < 4; ++s) {
            bf16x8 va0 = *(const bf16x8*)(VB + rb0 + roff[s]);
            bf16x8 va1 = *(const bf16x8*)(VB + rb1 + roff[s]);
            o0 = __builtin_amdgcn_mfma_f32_32x32x16_bf16(va0, pf[s], o0, 0, 0, 0);
            o1 = __builtin_amdgcn_mfma_f32_32x32x16_bf16(va1, pf[s], o1, 0, 0, 0);
        }
    };

    // prologue: stage tile 0 into buffer 0
    STAGE(0, (unsigned short*)Ks0, (unsigned short*)Vs0);
    __syncthreads();   // drains vmcnt

    // unroll-by-2 with STATIC buffer identities so prefetch writes (buf^1) are
    // provably distinct from current-buffer ds_reads (no spurious vmcnt waits).
#pragma unroll 1
    for (int kt = 0; kt <= qt; kt += 2) {
        if (kt + 1 <= qt) STAGE(kt + 1, (unsigned short*)Ks1, (unsigned short*)Vs1);
        COMPUTE(kt, Ks0, Vs0);
        __syncthreads();   // drains prefetch vmcnt; all waves done with buf0
        if (kt + 1 > qt) break;
        if (kt + 2 <= qt) STAGE(kt + 2, (unsigned short*)Ks0, (unsigned short*)Vs0);
        COMPUTE(kt + 1, Ks1, Vs1);
        __syncthreads();
    }

    // ---- epilogue: combine partner lsum, normalize, write O ----
    lsum += __shfl_xor(lsum, 32);
    const float inv = 1.f / lsum;
    unsigned short* op = O + ((size_t)(b * SQ + qrow)) * DM + h * 64;
#pragma unroll
    for (int r = 0; r < 16; r += 2) {
        const int d = (r & 3) + 8 * (r >> 2) + 4 * hi;   // d even; d+1 = next reg
        uint32_t w0 = (uint32_t)f2bf(o0[r] * inv) | ((uint32_t)f2bf(o0[r + 1] * inv) << 16);
        uint32_t w1 = (uint32_t)f2bf(o1[r] * inv) | ((uint32_t)f2bf(o1[r + 1] * inv) << 16);
        *(uint32_t*)(op + d) = w0;
        *(uint32_t*)(op + 32 + d) = w1;
    }
}

extern "C" void kernel_launch(void* const* d_in, const int* in_sizes, int n_in,
                              void* d_out, int out_size, void* d_ws, size_t ws_size,
                              hipStream_t stream) {
    const float* x  = (const float*)d_in[0];
    const float* Wq = (const float*)d_in[1];
    const float* bq = (const float*)d_in[2];
    const float* Wk = (const float*)d_in[3];
    const float* bk = (const float*)d_in[4];
    const float* Wv = (const float*)d_in[5];
    const float* bv = (const float*)d_in[6];
    const float* Wo = (const float*)d_in[7];
    const float* bo = (const float*)d_in[8];
    float* out = (float*)d_out;

    char* ws = (char*)d_ws;
    const size_t XB_BYTES = (size_t)M * DM * 2;        // 8 MB
    const size_t W_BYTES  = (size_t)DM * DM * 2;       // 2 MB
    const size_t H_BYTES  = (size_t)NB * NH * SQ * DK * 2; // 8 MB
    unsigned short* xb  = (unsigned short*)ws;                         // x bf16; later aliased as O
    unsigned short* wqt = (unsigned short*)(ws + XB_BYTES);            // wqt/wkt/wvt contiguous
    unsigned short* wkt = (unsigned short*)(ws + XB_BYTES + W_BYTES);
    unsigned short* wvt = (unsigned short*)(ws + XB_BYTES + 2 * W_BYTES);
    unsigned short* wot = (unsigned short*)(ws + XB_BYTES + 3 * W_BYTES);
    unsigned short* Qb  = (unsigned short*)(ws + XB_BYTES + 4 * W_BYTES);
    unsigned short* Kb  = (unsigned short*)(ws + XB_BYTES + 4 * W_BYTES + H_BYTES);
    unsigned short* Vb  = (unsigned short*)(ws + XB_BYTES + 4 * W_BYTES + 2 * H_BYTES); // [B,H,DK,S]

    cvt_x<<<(M * DM) / (256 * 8), 256, 0, stream>>>(x, xb);
    dim3 wgrid(32, 32), wblk(32, 8);
    cvt_w<<<wgrid, wblk, 0, stream>>>(Wq, wqt);
    cvt_w<<<wgrid, wblk, 0, stream>>>(Wk, wkt);
    cvt_w<<<wgrid, wblk, 0, stream>>>(Wv, wvt);
    cvt_w<<<wgrid, wblk, 0, stream>>>(Wo, wot);

    // fused QKV projection: N = 3072, grid 24x32 = 768 blocks = 3/CU
    gemm128<0><<<dim3(24, 32), 256, 0, stream>>>(xb, wqt, bq, bk, bv, Qb);

    attn32<<<NB * NH * 32, 128, 0, stream>>>(Qb, Kb, Vb, xb /* O aliases xb */);

    // output projection: N = 1024
    gemm128<1><<<dim3(8, 32), 256, 0, stream>>>(xb, wot, bo, bo, bo, out);
}

// Round 11
// 135.667 us; speedup vs baseline: 6.9005x; 1.1293x over previous
//
// r11: attn32 grid rebalance: g-major bid, per-CU qt quads {2u,31-2u,2u+1,30-2u} (sum 66 tiles/CU).
#include <hip/hip_runtime.h>
#include <stdint.h>

typedef __attribute__((ext_vector_type(8))) short bf16x8;
typedef __attribute__((ext_vector_type(8))) unsigned short ushort8;
typedef __attribute__((ext_vector_type(4))) float f32x4;
typedef __attribute__((ext_vector_type(16))) float f32x16;

constexpr int DM = 1024;   // d_model
constexpr int SQ = 2048;   // seq len
constexpr int NB = 2;      // batch
constexpr int NH = 16;     // heads
constexpr int DK = 64;     // head dim
constexpr int M  = NB * SQ; // 4096 rows

__device__ inline float bf2f(unsigned short u) {
    union { uint32_t i; float f; } c; c.i = ((uint32_t)u) << 16; return c.f;
}
__device__ inline unsigned short f2bf(float f) {
    union { float f; uint32_t i; } c; c.f = f;
    uint32_t r = c.i + 0x7FFFu + ((c.i >> 16) & 1u);   // round-to-nearest-even
    return (unsigned short)(r >> 16);
}
__device__ inline uint32_t cvtpk(float lo, float hi) {
    uint32_t r;
    asm("v_cvt_pk_bf16_f32 %0, %1, %2" : "=v"(r) : "v"(lo), "v"(hi));
    return r;
}
__device__ inline uint32_t sx32(uint32_t v) {   // exchange with partner lane (l ^ 32)
    return (uint32_t)__shfl_xor((int)v, 32);
}
__device__ inline bf16x8 mkfrag(uint32_t a, uint32_t b, uint32_t c, uint32_t d) {
    union { bf16x8 v; uint32_t u[4]; } m;
    m.u[0] = a; m.u[1] = b; m.u[2] = c; m.u[3] = d;
    return m.v;
}
__device__ inline void gload_lds16(const unsigned short* g, unsigned short* l) {
    __builtin_amdgcn_global_load_lds(
        (const __attribute__((address_space(1))) void*)g,
        (__attribute__((address_space(3))) void*)l, 16, 0, 0);
}

// ---------------- fp32 -> bf16 convert (x) ----------------
__global__ __launch_bounds__(256) void cvt_x(const float* __restrict__ x,
                                             unsigned short* __restrict__ xb) {
    int idx = (blockIdx.x * 256 + threadIdx.x) * 8;
    const float* p = x + idx;
    ushort8 o;
#pragma unroll
    for (int i = 0; i < 8; ++i) o[i] = f2bf(p[i]);
    *(ushort8*)(xb + idx) = o;
}

// ------------- fp32 [K][N] -> bf16 [N][K] transpose-convert -------------
__global__ __launch_bounds__(256) void cvt_w(const float* __restrict__ W,
                                             unsigned short* __restrict__ Wt) {
    __shared__ float tile[32][33];
    int tx = threadIdx.x, ty = threadIdx.y;
    int bx = blockIdx.x, by = blockIdx.y;
#pragma unroll
    for (int j = 0; j < 4; ++j)
        tile[ty + j * 8][tx] = W[(size_t)(by * 32 + ty + j * 8) * DM + bx * 32 + tx];
    __syncthreads();
#pragma unroll
    for (int j = 0; j < 4; ++j)
        Wt[(size_t)(bx * 32 + ty + j * 8) * DM + by * 32 + tx] = f2bf(tile[tx][ty + j * 8]);
}

// ---------------- bf16 MFMA GEMM, 128x128 tile, BK=32 (m97 structure) ----------------
// MODE 0: fused QKV. Q,K written [B,H,S,DK]; V written TRANSPOSED [B,H,DK,S].
// MODE 1: fp32 row-major [M,DM].
template <int MODE>
__global__ __launch_bounds__(256) void gemm128(const unsigned short* __restrict__ A,
                                               const unsigned short* __restrict__ Bt,
                                               const float* __restrict__ b0,
                                               const float* __restrict__ b1,
                                               const float* __restrict__ b2,
                                               void* __restrict__ outp) {
    constexpr int K = 1024;
    __shared__ __align__(16) unsigned short As[128 * 32];
    __shared__ __align__(16) unsigned short Bs[128 * 32];
    const int t = threadIdx.x;
    const int w = t >> 6, l = t & 63;
    const int l15 = l & 15, lg = l >> 4;
    const int wr = w >> 1, wc = w & 1;
    const int bx = blockIdx.x, by = blockIdx.y;

    f32x4 acc[4][4] = {};

    const int srow = l >> 2;
    const int sk   = (l & 3) * 8;
    const unsigned short* Abase = A  + (size_t)(by * 128) * K;
    const unsigned short* Bbase = Bt + (size_t)(bx * 128) * K;

    for (int k0 = 0; k0 < K; k0 += 32) {
#pragma unroll
        for (int i = 0; i < 2; ++i) {
            const int row = w * 32 + i * 16 + srow;
            gload_lds16(Abase + (size_t)row * K + k0 + sk, &As[row * 32 + sk]);
            gload_lds16(Bbase + (size_t)row * K + k0 + sk, &Bs[row * 32 + sk]);
        }
        __syncthreads();

        bf16x8 af[4], bfr[4];
#pragma unroll
        for (int mi = 0; mi < 4; ++mi)
            af[mi] = *(const bf16x8*)&As[(wr * 64 + mi * 16 + l15) * 32 + lg * 8];
#pragma unroll
        for (int ni = 0; ni < 4; ++ni)
            bfr[ni] = *(const bf16x8*)&Bs[(wc * 64 + ni * 16 + l15) * 32 + lg * 8];
#pragma unroll
        for (int mi = 0; mi < 4; ++mi)
#pragma unroll
            for (int ni = 0; ni < 4; ++ni)
                acc[mi][ni] = __builtin_amdgcn_mfma_f32_16x16x32_bf16(af[mi], bfr[ni], acc[mi][ni], 0, 0, 0);
        __syncthreads();
    }

#pragma unroll
    for (int ni = 0; ni < 4; ++ni) {
        const int n = bx * 128 + wc * 64 + ni * 16 + l15;
        float bias;
        if constexpr (MODE == 0) {
            const int mat = n >> 10;   // wave-uniform
            const float* bp = (mat == 0) ? b0 : (mat == 1) ? b1 : b2;
            bias = bp[n & 1023];
        } else {
            bias = b0[n];
        }
#pragma unroll
        for (int mi = 0; mi < 4; ++mi)
#pragma unroll
            for (int i = 0; i < 4; ++i) {
                const int m = by * 128 + wr * 64 + mi * 16 + lg * 4 + i;
                const float v = acc[mi][ni][i] + bias;
                if constexpr (MODE == 0) {
                    const int mat = n >> 10, c = n & 1023;
                    const int h = c >> 6, d = c & 63;
                    const int b = m >> 11, si = m & 2047;
                    size_t idx;
                    if (mat == 2)   // V transposed: [B,H,DK,S]
                        idx = ((size_t)(b * NH + h) * DK + d) * SQ + si;
                    else
                        idx = ((size_t)(b * NH + h) * SQ + si) * DK + d;
                    ((unsigned short*)outp)[(size_t)mat * (NB * NH * SQ * DK) + idx] = f2bf(v);
                } else {
                    ((float*)outp)[(size_t)m * DM + n] = v;
                }
            }
    }
}

// ---------------- 32x32-MFMA causal flash attention ----------------
// Q,K: bf16 [B,H,S,DK]; Vt: bf16 [B,H,DK,S]; O: bf16 [B,S,DM].
// Block: 2 waves x 32 q-rows = 64-row q-tile. Grid 1024, g-major:
//   bh = bid&31 (CU's 4 blocks share bh under mod-256 striping -> L2-local K/V)
//   qt(g): per-CU quad {2u, 31-2u, 2u+1, 30-2u} -> exactly 66 tiles per CU.
__global__ __launch_bounds__(128) void attn32(const unsigned short* __restrict__ Qg,
                                              const unsigned short* __restrict__ Kg,
                                              const unsigned short* __restrict__ Vtg,
                                              unsigned short* __restrict__ O) {
    __shared__ __align__(16) char Ks0[8192];   // [64 keys][64 dims], swizzled 16B slots
    __shared__ __align__(16) char Vs0[8192];   // [64 dims][64 keys], swizzled 16B slots
    __shared__ __align__(16) char Ks1[8192];
    __shared__ __align__(16) char Vs1[8192];
    const float NEG_INF = -__builtin_inff();

    const int bid = blockIdx.x;
    const int bh  = bid & 31;          // 0..31: same-bh blocks land on the same CU slot stream
    const int g   = bid >> 5;          // 0..31
    const int u = g & 7, sq = g >> 3;
    const int qt_even = 2 * u + (sq >> 1);          // sq=0 -> 2u ; sq=2 -> 2u+1
    const int qt_odd  = 31 - 2 * u - (sq >> 1);     // sq=1 -> 31-2u ; sq=3 -> 30-2u
    const int qt = (sq & 1) ? qt_odd : qt_even;     // bijective 0..31

    const int b = bh >> 4, h = bh & 15;
    const size_t base = (size_t)bh * SQ * DK;

    const int t = threadIdx.x;        // 0..127
    const int w = t >> 6, l = t & 63;
    const int l31 = l & 31, hi = l >> 5;
    const bool h0 = (hi == 0);

    // staging lane constants: lane covers LDS row (i*8 + l>>3), slot (l&7);
    // source chunk = slot ^ (row&7) = (l&7) ^ (l>>3)
    const int lrow = l >> 3;
    const int lchunk = (l & 7) ^ lrow;
    const unsigned short* ksrc0 = Kg + base + (size_t)lrow * DK + lchunk * 8;
    const unsigned short* vsrc0 = Vtg + (size_t)(bh * 64 + lrow) * SQ + lchunk * 8;

    // swizzled read byte-offsets for chunk c: slot = (hi + 2c) ^ (row&7)
    int roff[4];
#pragma unroll
    for (int c = 0; c < 4; ++c) roff[c] = (hi * 16 + 32 * c) ^ ((l & 7) << 4);
    const int rb0 = l31 * 128, rb1 = (32 + l31) * 128;

    const int qrow = qt * 64 + w * 32 + l31;
    const int qloc = w * 32 + l31;

    // Q B-fragments: lane holds Q[q=l31][hi*8 + 16c + j]
    bf16x8 qf[4];
    {
        const unsigned short* qp = Qg + base + (size_t)qrow * DK + hi * 8;
#pragma unroll
        for (int c = 0; c < 4; ++c) qf[c] = *(const bf16x8*)(qp + 16 * c);
    }

    float mrun = NEG_INF, lsum = 0.f;
    f32x16 o0 = {}, o1 = {};

    auto STAGE = [&](int kt, unsigned short* Kd, unsigned short* Vd) {
        if (w == 0) {
            const unsigned short* ks = ksrc0 + (size_t)kt * 64 * DK;
#pragma unroll
            for (int i = 0; i < 8; ++i)
                gload_lds16(ks + i * 8 * DK, Kd + i * 512 + l * 8);
        } else {
            const unsigned short* vs = vsrc0 + kt * 64;
#pragma unroll
            for (int i = 0; i < 8; ++i)
                gload_lds16(vs + (size_t)i * 8 * SQ, Vd + i * 512 + l * 8);
        }
    };

    auto COMPUTE = [&](int kt, const char* KB, const char* VB) {
        // ---- S^T = K Q^T : D[key][q], lane owns q = l31 ----
        f32x16 s0 = {}, s1 = {};
#pragma unroll
        for (int c = 0; c < 4; ++c) {
            bf16x8 ka0 = *(const bf16x8*)(KB + rb0 + roff[c]);
            bf16x8 ka1 = *(const bf16x8*)(KB + rb1 + roff[c]);
            s0 = __builtin_amdgcn_mfma_f32_32x32x16_bf16(ka0, qf[c], s0, 0, 0, 0);
            s1 = __builtin_amdgcn_mfma_f32_32x32x16_bf16(ka1, qf[c], s1, 0, 0, 0);
        }

        // ---- scale + causal mask + in-lane softmax ----
        const bool diag = (kt == qt);
        float p[32];
        float tm = NEG_INF;
#pragma unroll
        for (int r = 0; r < 16; ++r) {
            const int key0 = (r & 3) + 8 * (r >> 2) + 4 * hi;   // verified C/D row map
            float v0 = s0[r] * 0.125f;
            float v1 = s1[r] * 0.125f;
            if (diag && key0 > qloc) v0 = NEG_INF;
            if (diag && key0 + 32 > qloc) v1 = NEG_INF;
            p[r] = v0; p[16 + r] = v1;
            tm = fmaxf(tm, fmaxf(v0, v1));
        }
        tm = fmaxf(tm, __shfl_xor(tm, 32));   // partner holds other 32 keys
        const float mn = fmaxf(mrun, tm);
        const float corr = __expf(mrun - mn); // first tile: exp(-inf)=0
        mrun = mn;
        float ps = 0.f;
#pragma unroll
        for (int r = 0; r < 32; ++r) { p[r] = __expf(p[r] - mn); ps += p[r]; }
        lsum = lsum * corr + ps;
#pragma unroll
        for (int r = 0; r < 16; ++r) { o0[r] *= corr; o1[r] *= corr; }

        // ---- P -> bf16 packs + partner exchange -> PV B-fragments ----
        uint32_t pk[16];
#pragma unroll
        for (int i = 0; i < 16; ++i) pk[i] = cvtpk(p[2 * i], p[2 * i + 1]);
        const uint32_t X1 = sx32(h0 ? pk[2]  : pk[0]);
        const uint32_t X2 = sx32(h0 ? pk[3]  : pk[1]);
        const uint32_t X3 = sx32(h0 ? pk[6]  : pk[4]);
        const uint32_t X4 = sx32(h0 ? pk[7]  : pk[5]);
        const uint32_t X5 = sx32(h0 ? pk[10] : pk[8]);
        const uint32_t X6 = sx32(h0 ? pk[11] : pk[9]);
        const uint32_t X7 = sx32(h0 ? pk[14] : pk[12]);
        const uint32_t X8 = sx32(h0 ? pk[15] : pk[13]);
        bf16x8 pf[4];
        pf[0] = mkfrag(h0 ? pk[0]  : X1, h0 ? pk[1]  : X2, h0 ? X1 : pk[2],  h0 ? X2 : pk[3]);
        pf[1] = mkfrag(h0 ? pk[4]  : X3, h0 ? pk[5]  : X4, h0 ? X3 : pk[6],  h0 ? X4 : pk[7]);
        pf[2] = mkfrag(h0 ? pk[8]  : X5, h0 ? pk[9]  : X6, h0 ? X5 : pk[10], h0 ? X6 : pk[11]);
        pf[3] = mkfrag(h0 ? pk[12] : X7, h0 ? pk[13] : X8, h0 ? X7 : pk[14], h0 ? X8 : pk[15]);

        // ---- O^T += Vt P : D[d][q], lane owns q = l31 ----
#pragma unroll
        for (int s = 0; s < 4; ++s) {
            bf16x8 va0 = *(const bf16x8*)(VB + rb0 + roff[s]);
            bf16x8 va1 = *(const bf16x8*)(VB + rb1 + roff[s]);
            o0 = __builtin_amdgcn_mfma_f32_32x32x16_bf16(va0, pf[s], o0, 0, 0, 0);
            o1 = __builtin_amdgcn_mfma_f32_32x32x16_bf16(va1, pf[s], o1, 0, 0, 0);
        }
    };

    // prologue: stage tile 0 into buffer 0
    STAGE(0, (unsigned short*)Ks0, (unsigned short*)Vs0);
    __syncthreads();   // drains vmcnt

    // unroll-by-2 with STATIC buffer identities so prefetch writes (buf^1) are
    // provably distinct from current-buffer ds_reads (no spurious vmcnt waits).
#pragma unroll 1
    for (int kt = 0; kt <= qt; kt += 2) {
        if (kt + 1 <= qt) STAGE(kt + 1, (unsigned short*)Ks1, (unsigned short*)Vs1);
        COMPUTE(kt, Ks0, Vs0);
        __syncthreads();   // drains prefetch vmcnt; all waves done with buf0
        if (kt + 1 > qt) break;
        if (kt + 2 <= qt) STAGE(kt + 2, (unsigned short*)Ks0, (unsigned short*)Vs0);
        COMPUTE(kt + 1, Ks1, Vs1);
        __syncthreads();
    }

    // ---- epilogue: combine partner lsum, normalize, write O ----
    lsum += __shfl_xor(lsum, 32);
    const float inv = 1.f / lsum;
    unsigned short* op = O + ((size_t)(b * SQ + qrow)) * DM + h * 64;
#pragma unroll
    for (int r = 0; r < 16; r += 2) {
        const int d = (r & 3) + 8 * (r >> 2) + 4 * hi;   // d even; d+1 = next reg
        uint32_t w0 = (uint32_t)f2bf(o0[r] * inv) | ((uint32_t)f2bf(o0[r + 1] * inv) << 16);
        uint32_t w1 = (uint32_t)f2bf(o1[r] * inv) | ((uint32_t)f2bf(o1[r + 1] * inv) << 16);
        *(uint32_t*)(op + d) = w0;
        *(uint32_t*)(op + 32 + d) = w1;
    }
}

extern "C" void kernel_launch(void* const* d_in, const int* in_sizes, int n_in,
                              void* d_out, int out_size, void* d_ws, size_t ws_size,
                              hipStream_t stream) {
    const float* x  = (const float*)d_in[0];
    const float* Wq = (const float*)d_in[1];
    const float* bq = (const float*)d_in[2];
    const float* Wk = (const float*)d_in[3];
    const float* bk = (const float*)d_in[4];
    const float* Wv = (const float*)d_in[5];
    const float* bv = (const float*)d_in[6];
    const float* Wo = (const float*)d_in[7];
    const float* bo = (const float*)d_in[8];
    float* out = (float*)d_out;

    char* ws = (char*)d_ws;
    const size_t XB_BYTES = (size_t)M * DM * 2;        // 8 MB
    const size_t W_BYTES  = (size_t)DM * DM * 2;       // 2 MB
    const size_t H_BYTES  = (size_t)NB * NH * SQ * DK * 2; // 8 MB
    unsigned short* xb  = (unsigned short*)ws;                         // x bf16; later aliased as O
    unsigned short* wqt = (unsigned short*)(ws + XB_BYTES);            // wqt/wkt/wvt contiguous
    unsigned short* wkt = (unsigned short*)(ws + XB_BYTES + W_BYTES);
    unsigned short* wvt = (unsigned short*)(ws + XB_BYTES + 2 * W_BYTES);
    unsigned short* wot = (unsigned short*)(ws + XB_BYTES + 3 * W_BYTES);
    unsigned short* Qb  = (unsigned short*)(ws + XB_BYTES + 4 * W_BYTES);
    unsigned short* Kb  = (unsigned short*)(ws + XB_BYTES + 4 * W_BYTES + H_BYTES);
    unsigned short* Vb  = (unsigned short*)(ws + XB_BYTES + 4 * W_BYTES + 2 * H_BYTES); // [B,H,DK,S]

    cvt_x<<<(M * DM) / (256 * 8), 256, 0, stream>>>(x, xb);
    dim3 wgrid(32, 32), wblk(32, 8);
    cvt_w<<<wgrid, wblk, 0, stream>>>(Wq, wqt);
    cvt_w<<<wgrid, wblk, 0, stream>>>(Wk, wkt);
    cvt_w<<<wgrid, wblk, 0, stream>>>(Wv, wvt);
    cvt_w<<<wgrid, wblk, 0, stream>>>(Wo, wot);

    // fused QKV projection: N = 3072, grid 24x32 = 768 blocks = 3/CU
    gemm128<0><<<dim3(24, 32), 256, 0, stream>>>(xb, wqt, bq, bk, bv, Qb);

    attn32<<<NB * NH * 32, 128, 0, stream>>>(Qb, Kb, Vb, xb /* O aliases xb */);

    // output projection: N = 1024
    gemm128<1><<<dim3(8, 32), 256, 0, stream>>>(xb, wot, bo, bo, bo, out);
}